// Round 5
// baseline (8518.984 us; speedup 1.0000x reference)
//
#include <hip/hip_runtime.h>
#include <hip/hip_bf16.h>

// 2-layer GRU, B=128, S=2048, D=H=128, C=10. Inputs fp32.
//
// Phase 1 (all CUs): xp0[m,g] = x@W_ih0^T + biases, fp16 in d_ws (192 MiB).
// Phase 2 (this round): INTRA-WG producer/consumer wave split. 8 WGs x 768
//   threads (12 waves, 3/SIMD). Per WG (16 batch rows):
//     waves 0-3  (P): L0 chain. Each owns 32 hidden cols (2 N-tiles):
//        Whh0 MFMA (24) + gates; h0 double-buffered in LDS. xp0 prefetch
//        depth-2, packed fp16 pairs in VGPRs (register economy).
//     waves 4-11 (C): L1 chain, lagged one step (L1(t-1)): Wi1@h0(t-1) +
//        Wh1@h1(t-2) (24 MFMA) + gates; h1 double-buffered in LDS.
//   P and C chains run CONCURRENTLY between the same barriers on one CU ->
//   their serial latencies (ds_read -> MFMA chain -> trans gates) overlap.
//   R4's cross-CU ring/flags/memset deleted; communication is pure LDS.
//   Barrier = lgkmcnt-only s_barrier (global prefetches stay outstanding).
//   Both role loops execute identical barrier counts (2050 each).
//   Math operation-order-identical to R4 -> same absmax.
// Fallback: ws < XPB: proven single-kernel bf16 path (gru2_v1).

using bf16x8 = __attribute__((ext_vector_type(8))) short;
using s16x4  = __attribute__((ext_vector_type(4))) short;
using f32x4  = __attribute__((ext_vector_type(4))) float;
using f16x8  = __attribute__((ext_vector_type(8))) _Float16;
using f16x4  = __attribute__((ext_vector_type(4))) _Float16;

#define S_LEN 2048
#define D_IN  128
#define HID   128
#define B_TOT 128
#define BC    16
#define PAD   136
#define G3    384
#define M_TOT (B_TOT * S_LEN)

__device__ __forceinline__ float bf2f(short s) {
  unsigned int u = ((unsigned int)(unsigned short)s) << 16;
  float f; __builtin_memcpy(&f, &u, 4); return f;
}
__device__ __forceinline__ short f2bf(float f) {  // RNE
  unsigned int u; __builtin_memcpy(&u, &f, 4);
  u += 0x7fffu + ((u >> 16) & 1u);
  return (short)(u >> 16);
}
__device__ __forceinline__ float fast_sigmoid(float x) {
  return __builtin_amdgcn_rcpf(1.f + __expf(-x));
}
__device__ __forceinline__ float fast_tanh(float x) {
  return 2.f * __builtin_amdgcn_rcpf(1.f + __expf(-2.f * x)) - 1.f;
}
__device__ __forceinline__ f32x4 MFMA(bf16x8 a, bf16x8 b, f32x4 c) {
  return __builtin_amdgcn_mfma_f32_16x16x32_bf16(a, b, c, 0, 0, 0);
}
__device__ __forceinline__ f32x4 MFMA16(f16x8 a, f16x8 b, f32x4 c) {
  return __builtin_amdgcn_mfma_f32_16x16x32_f16(a, b, c, 0, 0, 0);
}
__device__ __forceinline__ void loadA(bf16x8 (&a)[4], const short* p) {
#pragma unroll
  for (int kq = 0; kq < 4; ++kq) a[kq] = *(const bf16x8*)(p + kq * 32);
}
__device__ __forceinline__ void loadA16(f16x8 (&a)[4], const _Float16* p) {
#pragma unroll
  for (int kq = 0; kq < 4; ++kq) a[kq] = *(const f16x8*)(p + kq * 32);
}
// Workgroup barrier WITHOUT the vmcnt(0) drain __syncthreads would emit.
__device__ __forceinline__ void wg_barrier() {
  asm volatile("s_waitcnt lgkmcnt(0)\n\ts_barrier" ::: "memory");
}
// unpack one fp16 half (lo/hi) of a packed u32 to float (v_cvt_f32_f16 sdwa)
__device__ __forceinline__ float f16p(unsigned pk, int hi) {
  unsigned short s = hi ? (unsigned short)(pk >> 16) : (unsigned short)pk;
  _Float16 h; __builtin_memcpy(&h, &s, 2); return (float)h;
}

// ============================ Phase 1 =====================================
__global__ __launch_bounds__(256, 1) void xp0_gemm(
    const float* __restrict__ x, const float* __restrict__ Wih0,
    const float* __restrict__ bih0, const float* __restrict__ bhh0,
    _Float16* __restrict__ xp0)
{
  __shared__ _Float16 wlds[96 * PAD];
  __shared__ float bfold[G3];

  const int tid = threadIdx.x;
  const int w = tid >> 6, lane = tid & 63, nw = lane & 15, quad = lane >> 4;
  const int m0 = blockIdx.x * 64 + w * 16;

  for (int g = tid; g < G3; g += 256)
    bfold[g] = bih0[g] + (g < 256 ? bhh0[g] : 0.f);

  f16x8 af[4];
  const int arow = m0 + nw;
#pragma unroll
  for (int kq = 0; kq < 4; ++kq) {
    const float* p = x + (size_t)arow * D_IN + kq * 32 + quad * 8;
    float4 v0 = *(const float4*)p, v1 = *(const float4*)(p + 4);
    af[kq] = (f16x8){(_Float16)v0.x, (_Float16)v0.y, (_Float16)v0.z, (_Float16)v0.w,
                     (_Float16)v1.x, (_Float16)v1.y, (_Float16)v1.z, (_Float16)v1.w};
  }

  for (int grp = 0; grp < 4; ++grp) {
    __syncthreads();
    for (int i = tid; i < 96 * 128 / 4; i += 256) {
      const int idx = i * 4, row = idx >> 7, cc = idx & 127;
      float4 v = *(const float4*)(Wih0 + (size_t)(grp * 96 + row) * 128 + cc);
      f16x4 s = { (_Float16)v.x, (_Float16)v.y, (_Float16)v.z, (_Float16)v.w };
      *(f16x4*)&wlds[row * PAD + cc] = s;
    }
    __syncthreads();

    f32x4 acc[6];
#pragma unroll
    for (int i = 0; i < 6; ++i) acc[i] = (f32x4){0.f, 0.f, 0.f, 0.f};
#pragma unroll
    for (int tI = 0; tI < 6; ++tI)
#pragma unroll
      for (int kq = 0; kq < 4; ++kq) {
        f16x8 b = *(const f16x8*)&wlds[(tI * 16 + nw) * PAD + kq * 32 + quad * 8];
        acc[tI] = MFMA16(af[kq], b, acc[tI]);
      }

#pragma unroll
    for (int tI = 0; tI < 6; ++tI) {
      const int g = grp * 96 + tI * 16 + nw;
      const float bb = bfold[g];
#pragma unroll
      for (int rr = 0; rr < 4; ++rr) {
        const int m = m0 + quad * 4 + rr;
        xp0[(size_t)m * G3 + g] = (_Float16)(acc[tI][rr] + bb);
      }
    }
  }
}

// ============================ Phase 2 =====================================
__device__ __forceinline__ void mm3f(const f16x8 (&a)[4], const f16x8 (&W)[3][4],
                                     f32x4& r, f32x4& z, f32x4& n) {
#pragma unroll
  for (int kq = 0; kq < 4; ++kq) {
    r = MFMA16(a[kq], W[0][kq], r);
    z = MFMA16(a[kq], W[1][kq], z);
    n = MFMA16(a[kq], W[2][kq], n);
  }
}

// ---------------- intra-WG producer/consumer kernel ------------------------
__global__ __launch_bounds__(768) void gru2_pc(
    const _Float16* __restrict__ xp0,
    const float* __restrict__ Whh0, const float* __restrict__ bhh0,
    const float* __restrict__ Wih1, const float* __restrict__ Whh1,
    const float* __restrict__ bih1, const float* __restrict__ bhh1,
    const float* __restrict__ Wout, const float* __restrict__ bout,
    float* __restrict__ out)
{
  __shared__ _Float16 h0f[2][BC * PAD];
  __shared__ _Float16 h1f[2][BC * PAD];

  const int tid  = threadIdx.x;
  const int wv   = tid >> 6;        // 0..11
  const int lane = tid & 63;
  const int nw   = lane & 15;
  const int quad = lane >> 4;
  const int b0   = blockIdx.x * BC;
  const int aoff = nw * PAD + quad * 8;

  for (int i = tid; i < 2 * BC * PAD; i += 768) {
    ((_Float16*)h0f)[i] = (_Float16)0.f;
    ((_Float16*)h1f)[i] = (_Float16)0.f;
  }

  if (wv < 4) {
    // ======================= P: layer-0 chain ============================
    const int u0 = wv * 32;          // this wave's 32-col slice (2 N-tiles)

    f16x8 W0[2][3][4];               // Whh0 B-frags, 96 VGPR
#pragma unroll
    for (int tI = 0; tI < 2; ++tI)
#pragma unroll
      for (int g = 0; g < 3; ++g)
#pragma unroll
        for (int kq = 0; kq < 4; ++kq) {
          const size_t o = (size_t)(g * 128 + u0 + tI * 16 + nw) * HID + kq * 32 + quad * 8;
#pragma unroll
          for (int e = 0; e < 8; ++e) W0[tI][g][kq][e] = (_Float16)Whh0[o + e];
        }
    const float b0nh[2] = { bhh0[256 + u0 + nw], bhh0[256 + u0 + 16 + nw] };

    // xp0 element offsets for rows b0+quad*4+rr at t=0, col base u0+nw
    unsigned off[4];
#pragma unroll
    for (int rr = 0; rr < 4; ++rr)
      off[rr] = (unsigned)((b0 + quad * 4 + rr) * S_LEN) * G3 + u0 + nw;

    // packed xp for 2 tiles x 3 gates x 4 rows = 24 halfs -> 12 u32
    auto loadPK = [&](unsigned (&P)[12], int t) {
      const unsigned tG = (unsigned)t * G3;
#pragma unroll
      for (int tI = 0; tI < 2; ++tI)
#pragma unroll
        for (int g = 0; g < 3; ++g)
#pragma unroll
          for (int p = 0; p < 2; ++p) {
            unsigned short lo, hi;
            __builtin_memcpy(&lo, &xp0[off[2 * p]     + tG + g * 128 + tI * 16], 2);
            __builtin_memcpy(&hi, &xp0[off[2 * p + 1] + tG + g * 128 + tI * 16], 2);
            P[(tI * 3 + g) * 2 + p] = (unsigned)lo | ((unsigned)hi << 16);
          }
    };

    unsigned PA[12], PB[12];
    loadPK(PA, 0);
    loadPK(PB, 1);
    f32x4 h0r[2] = {{0.f,0.f,0.f,0.f},{0.f,0.f,0.f,0.f}};

    auto pstep = [&](unsigned (&P)[12], const int t, const int pr, const int pw) {
      f16x8 a[4];
      loadA16(a, &h0f[pr][aoff]);           // h0(t-1), shared by both tiles
#pragma unroll
      for (int tI = 0; tI < 2; ++tI) {
        // acc-init carries xp (r,z) and bias (n) — same order as before
        f32x4 ar = { f16p(P[(tI*3+0)*2+0],0), f16p(P[(tI*3+0)*2+0],1),
                     f16p(P[(tI*3+0)*2+1],0), f16p(P[(tI*3+0)*2+1],1) };
        f32x4 az = { f16p(P[(tI*3+1)*2+0],0), f16p(P[(tI*3+1)*2+0],1),
                     f16p(P[(tI*3+1)*2+1],0), f16p(P[(tI*3+1)*2+1],1) };
        f32x4 ahn = { b0nh[tI], b0nh[tI], b0nh[tI], b0nh[tI] };
        mm3f(a, W0[tI], ar, az, ahn);
#pragma unroll
        for (int rr = 0; rr < 4; ++rr) {
          float r = fast_sigmoid(ar[rr]);
          float z = fast_sigmoid(az[rr]);
          float pn = f16p(P[(tI*3+2)*2 + (rr >> 1)], rr & 1);
          float n = fast_tanh(pn + r * ahn[rr]);
          float h = n + z * (h0r[tI][rr] - n);
          h0r[tI][rr] = h;
          h0f[pw][(quad * 4 + rr) * PAD + u0 + tI * 16 + nw] = (_Float16)h;
        }
      }
      // depth-2 prefetch: reload this buffer for t+2 (used 2 epochs later)
      const int tn = (t + 2 < S_LEN) ? t + 2 : t;
      loadPK(P, tn);
    };

    wg_barrier();
#pragma unroll 1
    for (int t2 = 0; t2 < S_LEN; t2 += 2) {
      pstep(PA, t2,     0, 1); wg_barrier();
      pstep(PB, t2 + 1, 1, 0); wg_barrier();
    }
    wg_barrier();   // C epilogue in flight
  } else {
    // ======================= C: layer-1 chain (lag 1) =====================
    const int u0c = (wv - 4) * 16;
    const int col = u0c + nw;

    const float b1r   = bih1[col]       + bhh1[col];
    const float b1z   = bih1[128 + col] + bhh1[128 + col];
    const float b1n_i = bih1[256 + col];
    const float b1n_h = bhh1[256 + col];

    f16x8 Wi1[3][4], Wh1[3][4];      // 96 VGPR
#pragma unroll
    for (int g = 0; g < 3; ++g)
#pragma unroll
      for (int kq = 0; kq < 4; ++kq) {
        const size_t o = (size_t)(g * 128 + col) * HID + kq * 32 + quad * 8;
#pragma unroll
        for (int e = 0; e < 8; ++e) {
          Wi1[g][kq][e] = (_Float16)Wih1[o + e];
          Wh1[g][kq][e] = (_Float16)Whh1[o + e];
        }
      }

    f32x4 h1r = {0.f, 0.f, 0.f, 0.f};

    auto cbody = [&](const int pr, _Float16* dst) {
      f16x8 a[4];
      f32x4 br  = {b1r, b1r, b1r, b1r};
      f32x4 bz  = {b1z, b1z, b1z, b1z};
      f32x4 bxn = {b1n_i, b1n_i, b1n_i, b1n_i};
      f32x4 bhn = {b1n_h, b1n_h, b1n_h, b1n_h};
      loadA16(a, &h0f[pr][aoff]);  mm3f(a, Wi1, br, bz, bxn);   // h0(t-1)
      loadA16(a, &h1f[pr][aoff]);  mm3f(a, Wh1, br, bz, bhn);   // h1(t-2)
#pragma unroll
      for (int rr = 0; rr < 4; ++rr) {
        float r = fast_sigmoid(br[rr]);
        float z = fast_sigmoid(bz[rr]);
        float n = fast_tanh(bxn[rr] + r * bhn[rr]);
        float h = n + z * (h1r[rr] - n);
        h1r[rr] = h;
        dst[(quad * 4 + rr) * PAD + col] = (_Float16)h;
      }
    };

    wg_barrier();
#pragma unroll 1
    for (int t2 = 0; t2 < S_LEN; t2 += 2) {
      // epoch t2 (even): computes L1(t2-1); skip at t2==0 (h1(-1)=0 stays)
      if (t2) cbody(0, h1f[1]);
      wg_barrier();
      cbody(1, h1f[0]);               // epoch t2+1 (odd): L1(t2)
      wg_barrier();
    }
    // epilogue: L1(2047): h0(2047) in h0f[0], h1(2046) in h1f[0] -> h1f[1]
    cbody(0, h1f[1]);
    wg_barrier();
  }

  // logits from final h1 (parity 1)
  if (tid < BC * 10) {
    const int b = tid / 10, c = tid % 10;
    float s = bout[c];
    const _Float16* hh = &h1f[1][b * PAD];
#pragma unroll 8
    for (int k = 0; k < HID; ++k)
      s += (float)hh[k] * Wout[c * HID + k];
    out[(size_t)(b0 + b) * 10 + c] = s;
  }
}

// ==================== Deep fallback: single-kernel, fp32 inputs ============
template<bool NSEP>
__device__ __forceinline__ void mm6(const bf16x8 (&a)[4], const bf16x8 (&W)[6][4],
                                    f32x4 (&acc)[6], f32x4 (&accn)[2]) {
#pragma unroll
  for (int tI = 0; tI < 6; ++tI)
#pragma unroll
    for (int kq = 0; kq < 4; ++kq) {
      if (NSEP && tI >= 4) accn[tI - 4] = MFMA(a[kq], W[tI][kq], accn[tI - 4]);
      else                 acc[tI]      = MFMA(a[kq], W[tI][kq], acc[tI]);
    }
}

__global__ __launch_bounds__(256, 1) void gru2_v1(
    const float* __restrict__ x,
    const float* __restrict__ Wih0, const float* __restrict__ Whh0,
    const float* __restrict__ bih0, const float* __restrict__ bhh0,
    const float* __restrict__ Wih1, const float* __restrict__ Whh1,
    const float* __restrict__ bih1, const float* __restrict__ bhh1,
    const float* __restrict__ Wout, const float* __restrict__ bout,
    float* __restrict__ out)
{
  __shared__ short h0hi[2][BC * PAD], h0lo[2][BC * PAD];
  __shared__ short h1hi[2][BC * PAD], h1lo[2][BC * PAD];
  __shared__ short xbhi[2][BC * PAD], xblo[2][BC * PAD];

  const int tid = threadIdx.x, w = tid >> 6, lane = tid & 63;
  const int nw = lane & 15, quad = lane >> 4, u0 = w * 32;
  const int b0 = blockIdx.x * BC;

  for (int i = tid; i < BC * PAD; i += 256) {
    h0hi[0][i] = 0; h0lo[0][i] = 0; h1hi[0][i] = 0; h1lo[0][i] = 0;
  }
  const size_t xelem = (size_t)(b0 + (tid >> 4)) * (size_t)(S_LEN * D_IN) + (size_t)((tid & 15) * 8);
  const int xsoff = (tid >> 4) * PAD + (tid & 15) * 8;

  auto load_x = [&](int t, bf16x8& xhi, bf16x8& xlo) {
    const size_t o = xelem + (size_t)t * D_IN;
    float4 v0 = *(const float4*)(x + o), v1 = *(const float4*)(x + o + 4);
    float v[8] = {v0.x, v0.y, v0.z, v0.w, v1.x, v1.y, v1.z, v1.w};
#pragma unroll
    for (int e = 0; e < 8; ++e) {
      short h = f2bf(v[e]); xhi[e] = h; xlo[e] = f2bf(v[e] - bf2f(h));
    }
  };
  { bf16x8 xh, xl; load_x(0, xh, xl);
    *(bf16x8*)&xbhi[0][xsoff] = xh; *(bf16x8*)&xblo[0][xsoff] = xl; }

  float brz0[4], bn0[4], brz1[4], bn1[4];
#pragma unroll
  for (int i = 0; i < 2; ++i) {
    const int c = u0 + i * 16 + nw;
    brz0[i] = bih0[c] + bhh0[c];     brz0[2 + i] = bih0[128 + c] + bhh0[128 + c];
    bn0[i] = bih0[256 + c];          bn0[2 + i] = bhh0[256 + c];
    brz1[i] = bih1[c] + bhh1[c];     brz1[2 + i] = bih1[128 + c] + bhh1[128 + c];
    bn1[i] = bih1[256 + c];          bn1[2 + i] = bhh1[256 + c];
  }

  bf16x8 W0[6][4], Wh0f[6][4], W1[6][4], Wh1f[6][4];
#pragma unroll
  for (int tI = 0; tI < 6; ++tI) {
    const int rb = (tI >> 1) * 128 + u0 + (tI & 1) * 16 + nw;
#pragma unroll
    for (int kq = 0; kq < 4; ++kq) {
      const size_t o = (size_t)rb * HID + kq * 32 + quad * 8;
#pragma unroll
      for (int e = 0; e < 8; ++e) {
        W0[tI][kq][e] = f2bf(Wih0[o + e]);  Wh0f[tI][kq][e] = f2bf(Whh0[o + e]);
        W1[tI][kq][e] = f2bf(Wih1[o + e]);  Wh1f[tI][kq][e] = f2bf(Whh1[o + e]);
      }
    }
  }

  f32x4 h0reg[2] = {{0,0,0,0},{0,0,0,0}}, h1reg[2] = {{0,0,0,0},{0,0,0,0}};
  const f32x4 ZV = {0.f, 0.f, 0.f, 0.f};
  __syncthreads();
  const int aoff = nw * PAD + quad * 8;

  auto gates = [&](const f32x4 (&acc)[6], const f32x4 (&accn)[2], f32x4 (&hreg)[2],
                   const float (&brz)[4], const float (&bn)[4],
                   short* dhi, short* dlo) {
#pragma unroll
    for (int i = 0; i < 2; ++i) {
      const int c = u0 + i * 16 + nw;
#pragma unroll
      for (int rr = 0; rr < 4; ++rr) {
        float rv = fast_sigmoid(acc[i][rr] + brz[i]);
        float zv = fast_sigmoid(acc[2 + i][rr] + brz[2 + i]);
        float nv = fast_tanh((acc[4 + i][rr] + bn[i]) + rv * (accn[i][rr] + bn[2 + i]));
        float h = (1.f - zv) * nv + zv * hreg[i][rr];
        hreg[i][rr] = h;
        short hi = f2bf(h);
        const int row = quad * 4 + rr;
        dhi[row * PAD + c] = hi;
        dlo[row * PAD + c] = f2bf(h - bf2f(hi));
      }
    }
  };

  for (int t = 0; t < S_LEN; ++t) {
    const int pr = t & 1, pw = pr ^ 1;
    const int t1 = (t + 1 < S_LEN) ? t + 1 : t;
    bf16x8 xh, xl; load_x(t1, xh, xl);

    f32x4 acc[6], accn[2];
#pragma unroll
    for (int i = 0; i < 6; ++i) acc[i] = ZV;
#pragma unroll
    for (int i = 0; i < 2; ++i) accn[i] = ZV;
    bf16x8 a[4];
    loadA(a, &xbhi[pr][aoff]); mm6<false>(a, W0, acc, accn);
    loadA(a, &xblo[pr][aoff]); mm6<false>(a, W0, acc, accn);
    loadA(a, &h0hi[pr][aoff]); mm6<true >(a, Wh0f, acc, accn);
    loadA(a, &h0lo[pr][aoff]); mm6<true >(a, Wh0f, acc, accn);
    gates(acc, accn, h0reg, brz0, bn0, h0hi[pw], h0lo[pw]);
    __syncthreads();

#pragma unroll
    for (int i = 0; i < 6; ++i) acc[i] = ZV;
#pragma unroll
    for (int i = 0; i < 2; ++i) accn[i] = ZV;
    loadA(a, &h0hi[pw][aoff]); mm6<false>(a, W1, acc, accn);
    loadA(a, &h0lo[pw][aoff]); mm6<false>(a, W1, acc, accn);
    loadA(a, &h1hi[pr][aoff]); mm6<true >(a, Wh1f, acc, accn);
    loadA(a, &h1lo[pr][aoff]); mm6<true >(a, Wh1f, acc, accn);
    *(bf16x8*)&xbhi[pw][xsoff] = xh;
    *(bf16x8*)&xblo[pw][xsoff] = xl;
    gates(acc, accn, h1reg, brz1, bn1, h1hi[pw], h1lo[pw]);
    __syncthreads();
  }

  if (tid < BC * 10) {
    const int b = tid / 10, c = tid % 10;
    float s = bout[c];
    const short* hh = &h1hi[0][b * PAD];
    const short* hl = &h1lo[0][b * PAD];
#pragma unroll 8
    for (int k = 0; k < HID; ++k)
      s += (bf2f(hh[k]) + bf2f(hl[k])) * Wout[c * HID + k];
    out[(size_t)(b0 + b) * 10 + c] = s;
  }
}

// ============================ Host =========================================
extern "C" void kernel_launch(void* const* d_in, const int* in_sizes, int n_in,
                              void* d_out, int out_size, void* d_ws, size_t ws_size,
                              hipStream_t stream) {
  (void)in_sizes; (void)n_in; (void)out_size;
  const float* x    = (const float*)d_in[0];
  const float* Wih0 = (const float*)d_in[1];
  const float* Whh0 = (const float*)d_in[2];
  const float* bih0 = (const float*)d_in[3];
  const float* bhh0 = (const float*)d_in[4];
  const float* Wih1 = (const float*)d_in[5];
  const float* Whh1 = (const float*)d_in[6];
  const float* bih1 = (const float*)d_in[7];
  const float* bhh1 = (const float*)d_in[8];
  const float* Wout = (const float*)d_in[9];
  const float* bout = (const float*)d_in[10];
  float* out = (float*)d_out;

  const size_t XPB = (size_t)M_TOT * G3 * sizeof(_Float16);   // 192 MiB

  if (ws_size >= XPB) {
    _Float16* xp0 = (_Float16*)d_ws;
    xp0_gemm<<<dim3(M_TOT / 64), dim3(256), 0, stream>>>(
        x, Wih0, bih0, bhh0, xp0);
    gru2_pc<<<dim3(B_TOT / BC), dim3(768), 0, stream>>>(
        xp0, Whh0, bhh0, Wih1, Whh1, bih1, bhh1, Wout, bout, out);
  } else {
    gru2_v1<<<dim3(B_TOT / BC), dim3(256), 0, stream>>>(
        x, Wih0, Whh0, bih0, bhh0, Wih1, Whh1, bih1, bhh1, Wout, bout, out);
  }
}

// Round 6
// 8477.332 us; speedup vs baseline: 1.0049x; 1.0049x over previous
//
#include <hip/hip_runtime.h>
#include <hip/hip_bf16.h>

// 2-layer GRU, B=128, S=2048, D=H=128, C=10. Inputs fp32.
//
// Phase 1 (all CUs): xp0[m,g] = x@W_ih0^T + biases, fp16 in d_ws (192 MiB).
// Phase 2: INTRA-WG producer/consumer wave split. 8 WGs x 768 threads
//   (12 waves, 3/SIMD). Per WG (16 batch rows):
//     waves 0-3  (P): L0 chain. Each owns 32 hidden cols (2 N-tiles):
//        Whh0 MFMA (24) + gates; h0 double-buffered in LDS. xp0 prefetch
//        depth-2, packed fp16 pairs in VGPRs.
//     waves 4-11 (C): L1 chain, lagged one step: Wi1@h0(t-1) + Wh1@h1(t-2)
//        (24 MFMA) + gates; h1 double-buffered in LDS.
//   P and C chains run CONCURRENTLY between the same barriers on one CU.
//   FIX (this round): __launch_bounds__(768, 3) — R5 omitted the min-waves
//   arg, compiler targeted ~6 waves/SIMD -> 84-VGPR budget -> ALL weight
//   fragments spilled to scratch (VGPR_Count=84 < the 96 needed for W0
//   alone) -> 3.5x regression. 3 waves/EU = 1 WG/CU -> 170-VGPR budget,
//   weights stay register-resident.
// Fallback: ws < XPB: proven single-kernel bf16 path (gru2_v1).

using bf16x8 = __attribute__((ext_vector_type(8))) short;
using s16x4  = __attribute__((ext_vector_type(4))) short;
using f32x4  = __attribute__((ext_vector_type(4))) float;
using f16x8  = __attribute__((ext_vector_type(8))) _Float16;
using f16x4  = __attribute__((ext_vector_type(4))) _Float16;

#define S_LEN 2048
#define D_IN  128
#define HID   128
#define B_TOT 128
#define BC    16
#define PAD   136
#define G3    384
#define M_TOT (B_TOT * S_LEN)

__device__ __forceinline__ float bf2f(short s) {
  unsigned int u = ((unsigned int)(unsigned short)s) << 16;
  float f; __builtin_memcpy(&f, &u, 4); return f;
}
__device__ __forceinline__ short f2bf(float f) {  // RNE
  unsigned int u; __builtin_memcpy(&u, &f, 4);
  u += 0x7fffu + ((u >> 16) & 1u);
  return (short)(u >> 16);
}
__device__ __forceinline__ float fast_sigmoid(float x) {
  return __builtin_amdgcn_rcpf(1.f + __expf(-x));
}
__device__ __forceinline__ float fast_tanh(float x) {
  return 2.f * __builtin_amdgcn_rcpf(1.f + __expf(-2.f * x)) - 1.f;
}
__device__ __forceinline__ f32x4 MFMA(bf16x8 a, bf16x8 b, f32x4 c) {
  return __builtin_amdgcn_mfma_f32_16x16x32_bf16(a, b, c, 0, 0, 0);
}
__device__ __forceinline__ f32x4 MFMA16(f16x8 a, f16x8 b, f32x4 c) {
  return __builtin_amdgcn_mfma_f32_16x16x32_f16(a, b, c, 0, 0, 0);
}
__device__ __forceinline__ void loadA(bf16x8 (&a)[4], const short* p) {
#pragma unroll
  for (int kq = 0; kq < 4; ++kq) a[kq] = *(const bf16x8*)(p + kq * 32);
}
__device__ __forceinline__ void loadA16(f16x8 (&a)[4], const _Float16* p) {
#pragma unroll
  for (int kq = 0; kq < 4; ++kq) a[kq] = *(const f16x8*)(p + kq * 32);
}
// Workgroup barrier WITHOUT the vmcnt(0) drain __syncthreads would emit.
__device__ __forceinline__ void wg_barrier() {
  asm volatile("s_waitcnt lgkmcnt(0)\n\ts_barrier" ::: "memory");
}
// unpack one fp16 half (lo/hi) of a packed u32 to float
__device__ __forceinline__ float f16p(unsigned pk, int hi) {
  unsigned short s = hi ? (unsigned short)(pk >> 16) : (unsigned short)pk;
  _Float16 h; __builtin_memcpy(&h, &s, 2); return (float)h;
}

// ============================ Phase 1 =====================================
__global__ __launch_bounds__(256, 1) void xp0_gemm(
    const float* __restrict__ x, const float* __restrict__ Wih0,
    const float* __restrict__ bih0, const float* __restrict__ bhh0,
    _Float16* __restrict__ xp0)
{
  __shared__ _Float16 wlds[96 * PAD];
  __shared__ float bfold[G3];

  const int tid = threadIdx.x;
  const int w = tid >> 6, lane = tid & 63, nw = lane & 15, quad = lane >> 4;
  const int m0 = blockIdx.x * 64 + w * 16;

  for (int g = tid; g < G3; g += 256)
    bfold[g] = bih0[g] + (g < 256 ? bhh0[g] : 0.f);

  f16x8 af[4];
  const int arow = m0 + nw;
#pragma unroll
  for (int kq = 0; kq < 4; ++kq) {
    const float* p = x + (size_t)arow * D_IN + kq * 32 + quad * 8;
    float4 v0 = *(const float4*)p, v1 = *(const float4*)(p + 4);
    af[kq] = (f16x8){(_Float16)v0.x, (_Float16)v0.y, (_Float16)v0.z, (_Float16)v0.w,
                     (_Float16)v1.x, (_Float16)v1.y, (_Float16)v1.z, (_Float16)v1.w};
  }

  for (int grp = 0; grp < 4; ++grp) {
    __syncthreads();
    for (int i = tid; i < 96 * 128 / 4; i += 256) {
      const int idx = i * 4, row = idx >> 7, cc = idx & 127;
      float4 v = *(const float4*)(Wih0 + (size_t)(grp * 96 + row) * 128 + cc);
      f16x4 s = { (_Float16)v.x, (_Float16)v.y, (_Float16)v.z, (_Float16)v.w };
      *(f16x4*)&wlds[row * PAD + cc] = s;
    }
    __syncthreads();

    f32x4 acc[6];
#pragma unroll
    for (int i = 0; i < 6; ++i) acc[i] = (f32x4){0.f, 0.f, 0.f, 0.f};
#pragma unroll
    for (int tI = 0; tI < 6; ++tI)
#pragma unroll
      for (int kq = 0; kq < 4; ++kq) {
        f16x8 b = *(const f16x8*)&wlds[(tI * 16 + nw) * PAD + kq * 32 + quad * 8];
        acc[tI] = MFMA16(af[kq], b, acc[tI]);
      }

#pragma unroll
    for (int tI = 0; tI < 6; ++tI) {
      const int g = grp * 96 + tI * 16 + nw;
      const float bb = bfold[g];
#pragma unroll
      for (int rr = 0; rr < 4; ++rr) {
        const int m = m0 + quad * 4 + rr;
        xp0[(size_t)m * G3 + g] = (_Float16)(acc[tI][rr] + bb);
      }
    }
  }
}

// ============================ Phase 2 =====================================
__device__ __forceinline__ void mm3f(const f16x8 (&a)[4], const f16x8 (&W)[3][4],
                                     f32x4& r, f32x4& z, f32x4& n) {
#pragma unroll
  for (int kq = 0; kq < 4; ++kq) {
    r = MFMA16(a[kq], W[0][kq], r);
    z = MFMA16(a[kq], W[1][kq], z);
    n = MFMA16(a[kq], W[2][kq], n);
  }
}

// ---------------- intra-WG producer/consumer kernel ------------------------
__global__ __launch_bounds__(768, 3) void gru2_pc(
    const _Float16* __restrict__ xp0,
    const float* __restrict__ Whh0, const float* __restrict__ bhh0,
    const float* __restrict__ Wih1, const float* __restrict__ Whh1,
    const float* __restrict__ bih1, const float* __restrict__ bhh1,
    const float* __restrict__ Wout, const float* __restrict__ bout,
    float* __restrict__ out)
{
  __shared__ _Float16 h0f[2][BC * PAD];
  __shared__ _Float16 h1f[2][BC * PAD];

  const int tid  = threadIdx.x;
  const int wv   = tid >> 6;        // 0..11
  const int lane = tid & 63;
  const int nw   = lane & 15;
  const int quad = lane >> 4;
  const int b0   = blockIdx.x * BC;
  const int aoff = nw * PAD + quad * 8;

  for (int i = tid; i < 2 * BC * PAD; i += 768) {
    ((_Float16*)h0f)[i] = (_Float16)0.f;
    ((_Float16*)h1f)[i] = (_Float16)0.f;
  }

  if (wv < 4) {
    // ======================= P: layer-0 chain ============================
    const int u0 = wv * 32;          // this wave's 32-col slice (2 N-tiles)

    f16x8 W0[2][3][4];               // Whh0 B-frags, 96 VGPR
#pragma unroll
    for (int tI = 0; tI < 2; ++tI)
#pragma unroll
      for (int g = 0; g < 3; ++g)
#pragma unroll
        for (int kq = 0; kq < 4; ++kq) {
          const size_t o = (size_t)(g * 128 + u0 + tI * 16 + nw) * HID + kq * 32 + quad * 8;
#pragma unroll
          for (int e = 0; e < 8; ++e) W0[tI][g][kq][e] = (_Float16)Whh0[o + e];
        }
    const float b0nh[2] = { bhh0[256 + u0 + nw], bhh0[256 + u0 + 16 + nw] };

    // xp0 element offsets for rows b0+quad*4+rr at t=0, col base u0+nw
    unsigned off[4];
#pragma unroll
    for (int rr = 0; rr < 4; ++rr)
      off[rr] = (unsigned)((b0 + quad * 4 + rr) * S_LEN) * G3 + u0 + nw;

    // packed xp for 2 tiles x 3 gates x 4 rows = 24 halfs -> 12 u32
    auto loadPK = [&](unsigned (&P)[12], int t) {
      const unsigned tG = (unsigned)t * G3;
#pragma unroll
      for (int tI = 0; tI < 2; ++tI)
#pragma unroll
        for (int g = 0; g < 3; ++g)
#pragma unroll
          for (int p = 0; p < 2; ++p) {
            unsigned short lo, hi;
            __builtin_memcpy(&lo, &xp0[off[2 * p]     + tG + g * 128 + tI * 16], 2);
            __builtin_memcpy(&hi, &xp0[off[2 * p + 1] + tG + g * 128 + tI * 16], 2);
            P[(tI * 3 + g) * 2 + p] = (unsigned)lo | ((unsigned)hi << 16);
          }
    };

    unsigned PA[12], PB[12];
    loadPK(PA, 0);
    loadPK(PB, 1);
    f32x4 h0r[2] = {{0.f,0.f,0.f,0.f},{0.f,0.f,0.f,0.f}};

    auto pstep = [&](unsigned (&P)[12], const int t, const int pr, const int pw) {
      f16x8 a[4];
      loadA16(a, &h0f[pr][aoff]);           // h0(t-1), shared by both tiles
#pragma unroll
      for (int tI = 0; tI < 2; ++tI) {
        // acc-init carries xp (r,z) and bias (n) — same order as before
        f32x4 ar = { f16p(P[(tI*3+0)*2+0],0), f16p(P[(tI*3+0)*2+0],1),
                     f16p(P[(tI*3+0)*2+1],0), f16p(P[(tI*3+0)*2+1],1) };
        f32x4 az = { f16p(P[(tI*3+1)*2+0],0), f16p(P[(tI*3+1)*2+0],1),
                     f16p(P[(tI*3+1)*2+1],0), f16p(P[(tI*3+1)*2+1],1) };
        f32x4 ahn = { b0nh[tI], b0nh[tI], b0nh[tI], b0nh[tI] };
        mm3f(a, W0[tI], ar, az, ahn);
#pragma unroll
        for (int rr = 0; rr < 4; ++rr) {
          float r = fast_sigmoid(ar[rr]);
          float z = fast_sigmoid(az[rr]);
          float pn = f16p(P[(tI*3+2)*2 + (rr >> 1)], rr & 1);
          float n = fast_tanh(pn + r * ahn[rr]);
          float h = n + z * (h0r[tI][rr] - n);
          h0r[tI][rr] = h;
          h0f[pw][(quad * 4 + rr) * PAD + u0 + tI * 16 + nw] = (_Float16)h;
        }
      }
      // depth-2 prefetch: reload this buffer for t+2 (used 2 epochs later)
      const int tn = (t + 2 < S_LEN) ? t + 2 : t;
      loadPK(P, tn);
    };

    wg_barrier();
#pragma unroll 1
    for (int t2 = 0; t2 < S_LEN; t2 += 2) {
      pstep(PA, t2,     0, 1); wg_barrier();
      pstep(PB, t2 + 1, 1, 0); wg_barrier();
    }
    wg_barrier();   // C epilogue in flight
  } else {
    // ======================= C: layer-1 chain (lag 1) =====================
    const int u0c = (wv - 4) * 16;
    const int col = u0c + nw;

    const float b1r   = bih1[col]       + bhh1[col];
    const float b1z   = bih1[128 + col] + bhh1[128 + col];
    const float b1n_i = bih1[256 + col];
    const float b1n_h = bhh1[256 + col];

    f16x8 Wi1[3][4], Wh1[3][4];      // 96 VGPR
#pragma unroll
    for (int g = 0; g < 3; ++g)
#pragma unroll
      for (int kq = 0; kq < 4; ++kq) {
        const size_t o = (size_t)(g * 128 + col) * HID + kq * 32 + quad * 8;
#pragma unroll
        for (int e = 0; e < 8; ++e) {
          Wi1[g][kq][e] = (_Float16)Wih1[o + e];
          Wh1[g][kq][e] = (_Float16)Whh1[o + e];
        }
      }

    f32x4 h1r = {0.f, 0.f, 0.f, 0.f};

    auto cbody = [&](const int pr, _Float16* dst) {
      f16x8 a[4];
      f32x4 br  = {b1r, b1r, b1r, b1r};
      f32x4 bz  = {b1z, b1z, b1z, b1z};
      f32x4 bxn = {b1n_i, b1n_i, b1n_i, b1n_i};
      f32x4 bhn = {b1n_h, b1n_h, b1n_h, b1n_h};
      loadA16(a, &h0f[pr][aoff]);  mm3f(a, Wi1, br, bz, bxn);   // h0(t-1)
      loadA16(a, &h1f[pr][aoff]);  mm3f(a, Wh1, br, bz, bhn);   // h1(t-2)
#pragma unroll
      for (int rr = 0; rr < 4; ++rr) {
        float r = fast_sigmoid(br[rr]);
        float z = fast_sigmoid(bz[rr]);
        float n = fast_tanh(bxn[rr] + r * bhn[rr]);
        float h = n + z * (h1r[rr] - n);
        h1r[rr] = h;
        dst[(quad * 4 + rr) * PAD + col] = (_Float16)h;
      }
    };

    wg_barrier();
#pragma unroll 1
    for (int t2 = 0; t2 < S_LEN; t2 += 2) {
      // epoch t2 (even): computes L1(t2-1); skip at t2==0 (h1(-1)=0 stays)
      if (t2) cbody(0, h1f[1]);
      wg_barrier();
      cbody(1, h1f[0]);               // epoch t2+1 (odd): L1(t2)
      wg_barrier();
    }
    // epilogue: L1(2047): h0(2047) in h0f[0], h1(2046) in h1f[0] -> h1f[1]
    cbody(0, h1f[1]);
    wg_barrier();
  }

  // logits from final h1 (parity 1)
  if (tid < BC * 10) {
    const int b = tid / 10, c = tid % 10;
    float s = bout[c];
    const _Float16* hh = &h1f[1][b * PAD];
#pragma unroll 8
    for (int k = 0; k < HID; ++k)
      s += (float)hh[k] * Wout[c * HID + k];
    out[(size_t)(b0 + b) * 10 + c] = s;
  }
}

// ==================== Deep fallback: single-kernel, fp32 inputs ============
template<bool NSEP>
__device__ __forceinline__ void mm6(const bf16x8 (&a)[4], const bf16x8 (&W)[6][4],
                                    f32x4 (&acc)[6], f32x4 (&accn)[2]) {
#pragma unroll
  for (int tI = 0; tI < 6; ++tI)
#pragma unroll
    for (int kq = 0; kq < 4; ++kq) {
      if (NSEP && tI >= 4) accn[tI - 4] = MFMA(a[kq], W[tI][kq], accn[tI - 4]);
      else                 acc[tI]      = MFMA(a[kq], W[tI][kq], acc[tI]);
    }
}

__global__ __launch_bounds__(256, 1) void gru2_v1(
    const float* __restrict__ x,
    const float* __restrict__ Wih0, const float* __restrict__ Whh0,
    const float* __restrict__ bih0, const float* __restrict__ bhh0,
    const float* __restrict__ Wih1, const float* __restrict__ Whh1,
    const float* __restrict__ bih1, const float* __restrict__ bhh1,
    const float* __restrict__ Wout, const float* __restrict__ bout,
    float* __restrict__ out)
{
  __shared__ short h0hi[2][BC * PAD], h0lo[2][BC * PAD];
  __shared__ short h1hi[2][BC * PAD], h1lo[2][BC * PAD];
  __shared__ short xbhi[2][BC * PAD], xblo[2][BC * PAD];

  const int tid = threadIdx.x, w = tid >> 6, lane = tid & 63;
  const int nw = lane & 15, quad = lane >> 4, u0 = w * 32;
  const int b0 = blockIdx.x * BC;

  for (int i = tid; i < BC * PAD; i += 256) {
    h0hi[0][i] = 0; h0lo[0][i] = 0; h1hi[0][i] = 0; h1lo[0][i] = 0;
  }
  const size_t xelem = (size_t)(b0 + (tid >> 4)) * (size_t)(S_LEN * D_IN) + (size_t)((tid & 15) * 8);
  const int xsoff = (tid >> 4) * PAD + (tid & 15) * 8;

  auto load_x = [&](int t, bf16x8& xhi, bf16x8& xlo) {
    const size_t o = xelem + (size_t)t * D_IN;
    float4 v0 = *(const float4*)(x + o), v1 = *(const float4*)(x + o + 4);
    float v[8] = {v0.x, v0.y, v0.z, v0.w, v1.x, v1.y, v1.z, v1.w};
#pragma unroll
    for (int e = 0; e < 8; ++e) {
      short h = f2bf(v[e]); xhi[e] = h; xlo[e] = f2bf(v[e] - bf2f(h));
    }
  };
  { bf16x8 xh, xl; load_x(0, xh, xl);
    *(bf16x8*)&xbhi[0][xsoff] = xh; *(bf16x8*)&xblo[0][xsoff] = xl; }

  float brz0[4], bn0[4], brz1[4], bn1[4];
#pragma unroll
  for (int i = 0; i < 2; ++i) {
    const int c = u0 + i * 16 + nw;
    brz0[i] = bih0[c] + bhh0[c];     brz0[2 + i] = bih0[128 + c] + bhh0[128 + c];
    bn0[i] = bih0[256 + c];          bn0[2 + i] = bhh0[256 + c];
    brz1[i] = bih1[c] + bhh1[c];     brz1[2 + i] = bih1[128 + c] + bhh1[128 + c];
    bn1[i] = bih1[256 + c];          bn1[2 + i] = bhh1[256 + c];
  }

  bf16x8 W0[6][4], Wh0f[6][4], W1[6][4], Wh1f[6][4];
#pragma unroll
  for (int tI = 0; tI < 6; ++tI) {
    const int rb = (tI >> 1) * 128 + u0 + (tI & 1) * 16 + nw;
#pragma unroll
    for (int kq = 0; kq < 4; ++kq) {
      const size_t o = (size_t)rb * HID + kq * 32 + quad * 8;
#pragma unroll
      for (int e = 0; e < 8; ++e) {
        W0[tI][kq][e] = f2bf(Wih0[o + e]);  Wh0f[tI][kq][e] = f2bf(Whh0[o + e]);
        W1[tI][kq][e] = f2bf(Wih1[o + e]);  Wh1f[tI][kq][e] = f2bf(Whh1[o + e]);
      }
    }
  }

  f32x4 h0reg[2] = {{0,0,0,0},{0,0,0,0}}, h1reg[2] = {{0,0,0,0},{0,0,0,0}};
  const f32x4 ZV = {0.f, 0.f, 0.f, 0.f};
  __syncthreads();
  const int aoff = nw * PAD + quad * 8;

  auto gates = [&](const f32x4 (&acc)[6], const f32x4 (&accn)[2], f32x4 (&hreg)[2],
                   const float (&brz)[4], const float (&bn)[4],
                   short* dhi, short* dlo) {
#pragma unroll
    for (int i = 0; i < 2; ++i) {
      const int c = u0 + i * 16 + nw;
#pragma unroll
      for (int rr = 0; rr < 4; ++rr) {
        float rv = fast_sigmoid(acc[i][rr] + brz[i]);
        float zv = fast_sigmoid(acc[2 + i][rr] + brz[2 + i]);
        float nv = fast_tanh((acc[4 + i][rr] + bn[i]) + rv * (accn[i][rr] + bn[2 + i]));
        float h = (1.f - zv) * nv + zv * hreg[i][rr];
        hreg[i][rr] = h;
        short hi = f2bf(h);
        const int row = quad * 4 + rr;
        dhi[row * PAD + c] = hi;
        dlo[row * PAD + c] = f2bf(h - bf2f(hi));
      }
    }
  };

  for (int t = 0; t < S_LEN; ++t) {
    const int pr = t & 1, pw = pr ^ 1;
    const int t1 = (t + 1 < S_LEN) ? t + 1 : t;
    bf16x8 xh, xl; load_x(t1, xh, xl);

    f32x4 acc[6], accn[2];
#pragma unroll
    for (int i = 0; i < 6; ++i) acc[i] = ZV;
#pragma unroll
    for (int i = 0; i < 2; ++i) accn[i] = ZV;
    bf16x8 a[4];
    loadA(a, &xbhi[pr][aoff]); mm6<false>(a, W0, acc, accn);
    loadA(a, &xblo[pr][aoff]); mm6<false>(a, W0, acc, accn);
    loadA(a, &h0hi[pr][aoff]); mm6<true >(a, Wh0f, acc, accn);
    loadA(a, &h0lo[pr][aoff]); mm6<true >(a, Wh0f, acc, accn);
    gates(acc, accn, h0reg, brz0, bn0, h0hi[pw], h0lo[pw]);
    __syncthreads();

#pragma unroll
    for (int i = 0; i < 6; ++i) acc[i] = ZV;
#pragma unroll
    for (int i = 0; i < 2; ++i) accn[i] = ZV;
    loadA(a, &h0hi[pw][aoff]); mm6<false>(a, W1, acc, accn);
    loadA(a, &h0lo[pw][aoff]); mm6<false>(a, W1, acc, accn);
    loadA(a, &h1hi[pr][aoff]); mm6<true >(a, Wh1f, acc, accn);
    loadA(a, &h1lo[pr][aoff]); mm6<true >(a, Wh1f, acc, accn);
    *(bf16x8*)&xbhi[pw][xsoff] = xh;
    *(bf16x8*)&xblo[pw][xsoff] = xl;
    gates(acc, accn, h1reg, brz1, bn1, h1hi[pw], h1lo[pw]);
    __syncthreads();
  }

  if (tid < BC * 10) {
    const int b = tid / 10, c = tid % 10;
    float s = bout[c];
    const short* hh = &h1hi[0][b * PAD];
    const short* hl = &h1lo[0][b * PAD];
#pragma unroll 8
    for (int k = 0; k < HID; ++k)
      s += (bf2f(hh[k]) + bf2f(hl[k])) * Wout[c * HID + k];
    out[(size_t)(b0 + b) * 10 + c] = s;
  }
}

// ============================ Host =========================================
extern "C" void kernel_launch(void* const* d_in, const int* in_sizes, int n_in,
                              void* d_out, int out_size, void* d_ws, size_t ws_size,
                              hipStream_t stream) {
  (void)in_sizes; (void)n_in; (void)out_size;
  const float* x    = (const float*)d_in[0];
  const float* Wih0 = (const float*)d_in[1];
  const float* Whh0 = (const float*)d_in[2];
  const float* bih0 = (const float*)d_in[3];
  const float* bhh0 = (const float*)d_in[4];
  const float* Wih1 = (const float*)d_in[5];
  const float* Whh1 = (const float*)d_in[6];
  const float* bih1 = (const float*)d_in[7];
  const float* bhh1 = (const float*)d_in[8];
  const float* Wout = (const float*)d_in[9];
  const float* bout = (const float*)d_in[10];
  float* out = (float*)d_out;

  const size_t XPB = (size_t)M_TOT * G3 * sizeof(_Float16);   // 192 MiB

  if (ws_size >= XPB) {
    _Float16* xp0 = (_Float16*)d_ws;
    xp0_gemm<<<dim3(M_TOT / 64), dim3(256), 0, stream>>>(
        x, Wih0, bih0, bhh0, xp0);
    gru2_pc<<<dim3(B_TOT / BC), dim3(768), 0, stream>>>(
        xp0, Whh0, bhh0, Wih1, Whh1, bih1, bhh1, Wout, bout, out);
  } else {
    gru2_v1<<<dim3(B_TOT / BC), dim3(256), 0, stream>>>(
        x, Wih0, Whh0, bih0, bhh0, Wih1, Whh1, bih1, bhh1, Wout, bout, out);
  }
}

// Round 7
// 8464.299 us; speedup vs baseline: 1.0065x; 1.0015x over previous
//
#include <hip/hip_runtime.h>
#include <hip/hip_bf16.h>

// 2-layer GRU, B=128, S=2048, D=H=128, C=10. Inputs fp32.
//
// Phase 1 (all CUs): xp0[m,g] = x@W_ih0^T + biases, fp16 in d_ws (192 MiB).
// Phase 2: INTRA-WG producer/consumer wave split. 8 WGs x 768 threads
//   (12 waves, 3/SIMD). Per WG (16 batch rows):
//     waves 0-3  (P): L0 chain, 32 hidden cols each: Whh0 MFMA (24) + gates;
//        h0 double-buffered in LDS; xp0 prefetch depth-2 (packed fp16).
//     waves 4-11 (C): L1 chain, lagged one step: Wi1@h0(t-1) + Wh1@h1(t-2)
//        (24 MFMA) + gates; h1 double-buffered in LDS.
//   P and C chains run CONCURRENTLY between the same barriers on one CU.
//   FIX (this round): __launch_bounds__'s 2nd arg is only a MINIMUM
//   waves-per-EU; the compiler chose 6/SIMD (2 WGs/CU, 85-VGPR budget) and
//   spilled all weight fragments (R5/R6: VGPR_Count=84, 8.3ms). Pin the
//   occupancy with amdgpu_waves_per_eu(3,3): exactly 3 waves/SIMD -> 170
//   VGPR budget -> weights register-resident (P~164, C~140).
// Fallback: ws < XPB: proven single-kernel bf16 path (gru2_v1).

using bf16x8 = __attribute__((ext_vector_type(8))) short;
using s16x4  = __attribute__((ext_vector_type(4))) short;
using f32x4  = __attribute__((ext_vector_type(4))) float;
using f16x8  = __attribute__((ext_vector_type(8))) _Float16;
using f16x4  = __attribute__((ext_vector_type(4))) _Float16;

#define S_LEN 2048
#define D_IN  128
#define HID   128
#define B_TOT 128
#define BC    16
#define PAD   136
#define G3    384
#define M_TOT (B_TOT * S_LEN)

__device__ __forceinline__ float bf2f(short s) {
  unsigned int u = ((unsigned int)(unsigned short)s) << 16;
  float f; __builtin_memcpy(&f, &u, 4); return f;
}
__device__ __forceinline__ short f2bf(float f) {  // RNE
  unsigned int u; __builtin_memcpy(&u, &f, 4);
  u += 0x7fffu + ((u >> 16) & 1u);
  return (short)(u >> 16);
}
__device__ __forceinline__ float fast_sigmoid(float x) {
  return __builtin_amdgcn_rcpf(1.f + __expf(-x));
}
__device__ __forceinline__ float fast_tanh(float x) {
  return 2.f * __builtin_amdgcn_rcpf(1.f + __expf(-2.f * x)) - 1.f;
}
__device__ __forceinline__ f32x4 MFMA(bf16x8 a, bf16x8 b, f32x4 c) {
  return __builtin_amdgcn_mfma_f32_16x16x32_bf16(a, b, c, 0, 0, 0);
}
__device__ __forceinline__ f32x4 MFMA16(f16x8 a, f16x8 b, f32x4 c) {
  return __builtin_amdgcn_mfma_f32_16x16x32_f16(a, b, c, 0, 0, 0);
}
__device__ __forceinline__ void loadA(bf16x8 (&a)[4], const short* p) {
#pragma unroll
  for (int kq = 0; kq < 4; ++kq) a[kq] = *(const bf16x8*)(p + kq * 32);
}
__device__ __forceinline__ void loadA16(f16x8 (&a)[4], const _Float16* p) {
#pragma unroll
  for (int kq = 0; kq < 4; ++kq) a[kq] = *(const f16x8*)(p + kq * 32);
}
// Workgroup barrier WITHOUT the vmcnt(0) drain __syncthreads would emit.
__device__ __forceinline__ void wg_barrier() {
  asm volatile("s_waitcnt lgkmcnt(0)\n\ts_barrier" ::: "memory");
}
// unpack one fp16 half (lo/hi) of a packed u32 to float
__device__ __forceinline__ float f16p(unsigned pk, int hi) {
  unsigned short s = hi ? (unsigned short)(pk >> 16) : (unsigned short)pk;
  _Float16 h; __builtin_memcpy(&h, &s, 2); return (float)h;
}

// ============================ Phase 1 =====================================
__global__ __launch_bounds__(256, 1) void xp0_gemm(
    const float* __restrict__ x, const float* __restrict__ Wih0,
    const float* __restrict__ bih0, const float* __restrict__ bhh0,
    _Float16* __restrict__ xp0)
{
  __shared__ _Float16 wlds[96 * PAD];
  __shared__ float bfold[G3];

  const int tid = threadIdx.x;
  const int w = tid >> 6, lane = tid & 63, nw = lane & 15, quad = lane >> 4;
  const int m0 = blockIdx.x * 64 + w * 16;

  for (int g = tid; g < G3; g += 256)
    bfold[g] = bih0[g] + (g < 256 ? bhh0[g] : 0.f);

  f16x8 af[4];
  const int arow = m0 + nw;
#pragma unroll
  for (int kq = 0; kq < 4; ++kq) {
    const float* p = x + (size_t)arow * D_IN + kq * 32 + quad * 8;
    float4 v0 = *(const float4*)p, v1 = *(const float4*)(p + 4);
    af[kq] = (f16x8){(_Float16)v0.x, (_Float16)v0.y, (_Float16)v0.z, (_Float16)v0.w,
                     (_Float16)v1.x, (_Float16)v1.y, (_Float16)v1.z, (_Float16)v1.w};
  }

  for (int grp = 0; grp < 4; ++grp) {
    __syncthreads();
    for (int i = tid; i < 96 * 128 / 4; i += 256) {
      const int idx = i * 4, row = idx >> 7, cc = idx & 127;
      float4 v = *(const float4*)(Wih0 + (size_t)(grp * 96 + row) * 128 + cc);
      f16x4 s = { (_Float16)v.x, (_Float16)v.y, (_Float16)v.z, (_Float16)v.w };
      *(f16x4*)&wlds[row * PAD + cc] = s;
    }
    __syncthreads();

    f32x4 acc[6];
#pragma unroll
    for (int i = 0; i < 6; ++i) acc[i] = (f32x4){0.f, 0.f, 0.f, 0.f};
#pragma unroll
    for (int tI = 0; tI < 6; ++tI)
#pragma unroll
      for (int kq = 0; kq < 4; ++kq) {
        f16x8 b = *(const f16x8*)&wlds[(tI * 16 + nw) * PAD + kq * 32 + quad * 8];
        acc[tI] = MFMA16(af[kq], b, acc[tI]);
      }

#pragma unroll
    for (int tI = 0; tI < 6; ++tI) {
      const int g = grp * 96 + tI * 16 + nw;
      const float bb = bfold[g];
#pragma unroll
      for (int rr = 0; rr < 4; ++rr) {
        const int m = m0 + quad * 4 + rr;
        xp0[(size_t)m * G3 + g] = (_Float16)(acc[tI][rr] + bb);
      }
    }
  }
}

// ============================ Phase 2 =====================================
__device__ __forceinline__ void mm3f(const f16x8 (&a)[4], const f16x8 (&W)[3][4],
                                     f32x4& r, f32x4& z, f32x4& n) {
#pragma unroll
  for (int kq = 0; kq < 4; ++kq) {
    r = MFMA16(a[kq], W[0][kq], r);
    z = MFMA16(a[kq], W[1][kq], z);
    n = MFMA16(a[kq], W[2][kq], n);
  }
}

// ---------------- intra-WG producer/consumer kernel ------------------------
__global__ __launch_bounds__(768)
__attribute__((amdgpu_waves_per_eu(3, 3)))
void gru2_pc(
    const _Float16* __restrict__ xp0,
    const float* __restrict__ Whh0, const float* __restrict__ bhh0,
    const float* __restrict__ Wih1, const float* __restrict__ Whh1,
    const float* __restrict__ bih1, const float* __restrict__ bhh1,
    const float* __restrict__ Wout, const float* __restrict__ bout,
    float* __restrict__ out)
{
  __shared__ _Float16 h0f[2][BC * PAD];
  __shared__ _Float16 h1f[2][BC * PAD];

  const int tid  = threadIdx.x;
  const int wv   = tid >> 6;        // 0..11
  const int lane = tid & 63;
  const int nw   = lane & 15;
  const int quad = lane >> 4;
  const int b0   = blockIdx.x * BC;
  const int aoff = nw * PAD + quad * 8;

  for (int i = tid; i < 2 * BC * PAD; i += 768) {
    ((_Float16*)h0f)[i] = (_Float16)0.f;
    ((_Float16*)h1f)[i] = (_Float16)0.f;
  }

  if (wv < 4) {
    // ======================= P: layer-0 chain ============================
    const int u0 = wv * 32;          // this wave's 32-col slice (2 N-tiles)

    f16x8 W0[2][3][4];               // Whh0 B-frags, 96 VGPR
#pragma unroll
    for (int tI = 0; tI < 2; ++tI)
#pragma unroll
      for (int g = 0; g < 3; ++g)
#pragma unroll
        for (int kq = 0; kq < 4; ++kq) {
          const size_t o = (size_t)(g * 128 + u0 + tI * 16 + nw) * HID + kq * 32 + quad * 8;
#pragma unroll
          for (int e = 0; e < 8; ++e) W0[tI][g][kq][e] = (_Float16)Whh0[o + e];
        }
    const float b0nh[2] = { bhh0[256 + u0 + nw], bhh0[256 + u0 + 16 + nw] };

    // xp0 element offsets for rows b0+quad*4+rr at t=0, col base u0+nw
    unsigned off[4];
#pragma unroll
    for (int rr = 0; rr < 4; ++rr)
      off[rr] = (unsigned)((b0 + quad * 4 + rr) * S_LEN) * G3 + u0 + nw;

    // packed xp for 2 tiles x 3 gates x 4 rows = 24 halfs -> 12 u32
    auto loadPK = [&](unsigned (&P)[12], int t) {
      const unsigned tG = (unsigned)t * G3;
#pragma unroll
      for (int tI = 0; tI < 2; ++tI)
#pragma unroll
        for (int g = 0; g < 3; ++g)
#pragma unroll
          for (int p = 0; p < 2; ++p) {
            unsigned short lo, hi;
            __builtin_memcpy(&lo, &xp0[off[2 * p]     + tG + g * 128 + tI * 16], 2);
            __builtin_memcpy(&hi, &xp0[off[2 * p + 1] + tG + g * 128 + tI * 16], 2);
            P[(tI * 3 + g) * 2 + p] = (unsigned)lo | ((unsigned)hi << 16);
          }
    };

    unsigned PA[12], PB[12];
    loadPK(PA, 0);
    loadPK(PB, 1);
    f32x4 h0r[2] = {{0.f,0.f,0.f,0.f},{0.f,0.f,0.f,0.f}};

    auto pstep = [&](unsigned (&P)[12], const int t, const int pr, const int pw) {
      f16x8 a[4];
      loadA16(a, &h0f[pr][aoff]);           // h0(t-1), shared by both tiles
#pragma unroll
      for (int tI = 0; tI < 2; ++tI) {
        // acc-init carries xp (r,z) and bias (n) — same order as before
        f32x4 ar = { f16p(P[(tI*3+0)*2+0],0), f16p(P[(tI*3+0)*2+0],1),
                     f16p(P[(tI*3+0)*2+1],0), f16p(P[(tI*3+0)*2+1],1) };
        f32x4 az = { f16p(P[(tI*3+1)*2+0],0), f16p(P[(tI*3+1)*2+0],1),
                     f16p(P[(tI*3+1)*2+1],0), f16p(P[(tI*3+1)*2+1],1) };
        f32x4 ahn = { b0nh[tI], b0nh[tI], b0nh[tI], b0nh[tI] };
        mm3f(a, W0[tI], ar, az, ahn);
#pragma unroll
        for (int rr = 0; rr < 4; ++rr) {
          float r = fast_sigmoid(ar[rr]);
          float z = fast_sigmoid(az[rr]);
          float pn = f16p(P[(tI*3+2)*2 + (rr >> 1)], rr & 1);
          float n = fast_tanh(pn + r * ahn[rr]);
          float h = n + z * (h0r[tI][rr] - n);
          h0r[tI][rr] = h;
          h0f[pw][(quad * 4 + rr) * PAD + u0 + tI * 16 + nw] = (_Float16)h;
        }
      }
      // depth-2 prefetch: reload this buffer for t+2 (used 2 epochs later)
      const int tn = (t + 2 < S_LEN) ? t + 2 : t;
      loadPK(P, tn);
    };

    wg_barrier();
#pragma unroll 1
    for (int t2 = 0; t2 < S_LEN; t2 += 2) {
      pstep(PA, t2,     0, 1); wg_barrier();
      pstep(PB, t2 + 1, 1, 0); wg_barrier();
    }
    wg_barrier();   // C epilogue in flight
  } else {
    // ======================= C: layer-1 chain (lag 1) =====================
    const int u0c = (wv - 4) * 16;
    const int col = u0c + nw;

    const float b1r   = bih1[col]       + bhh1[col];
    const float b1z   = bih1[128 + col] + bhh1[128 + col];
    const float b1n_i = bih1[256 + col];
    const float b1n_h = bhh1[256 + col];

    f16x8 Wi1[3][4], Wh1[3][4];      // 96 VGPR
#pragma unroll
    for (int g = 0; g < 3; ++g)
#pragma unroll
      for (int kq = 0; kq < 4; ++kq) {
        const size_t o = (size_t)(g * 128 + col) * HID + kq * 32 + quad * 8;
#pragma unroll
        for (int e = 0; e < 8; ++e) {
          Wi1[g][kq][e] = (_Float16)Wih1[o + e];
          Wh1[g][kq][e] = (_Float16)Whh1[o + e];
        }
      }

    f32x4 h1r = {0.f, 0.f, 0.f, 0.f};

    auto cbody = [&](const int pr, _Float16* dst) {
      f16x8 a[4];
      f32x4 br  = {b1r, b1r, b1r, b1r};
      f32x4 bz  = {b1z, b1z, b1z, b1z};
      f32x4 bxn = {b1n_i, b1n_i, b1n_i, b1n_i};
      f32x4 bhn = {b1n_h, b1n_h, b1n_h, b1n_h};
      loadA16(a, &h0f[pr][aoff]);  mm3f(a, Wi1, br, bz, bxn);   // h0(t-1)
      loadA16(a, &h1f[pr][aoff]);  mm3f(a, Wh1, br, bz, bhn);   // h1(t-2)
#pragma unroll
      for (int rr = 0; rr < 4; ++rr) {
        float r = fast_sigmoid(br[rr]);
        float z = fast_sigmoid(bz[rr]);
        float n = fast_tanh(bxn[rr] + r * bhn[rr]);
        float h = n + z * (h1r[rr] - n);
        h1r[rr] = h;
        dst[(quad * 4 + rr) * PAD + col] = (_Float16)h;
      }
    };

    wg_barrier();
#pragma unroll 1
    for (int t2 = 0; t2 < S_LEN; t2 += 2) {
      // epoch t2 (even): computes L1(t2-1); skip at t2==0 (h1(-1)=0 stays)
      if (t2) cbody(0, h1f[1]);
      wg_barrier();
      cbody(1, h1f[0]);               // epoch t2+1 (odd): L1(t2)
      wg_barrier();
    }
    // epilogue: L1(2047): h0(2047) in h0f[0], h1(2046) in h1f[0] -> h1f[1]
    cbody(0, h1f[1]);
    wg_barrier();
  }

  // logits from final h1 (parity 1)
  if (tid < BC * 10) {
    const int b = tid / 10, c = tid % 10;
    float s = bout[c];
    const _Float16* hh = &h1f[1][b * PAD];
#pragma unroll 8
    for (int k = 0; k < HID; ++k)
      s += (float)hh[k] * Wout[c * HID + k];
    out[(size_t)(b0 + b) * 10 + c] = s;
  }
}

// ==================== Deep fallback: single-kernel, fp32 inputs ============
template<bool NSEP>
__device__ __forceinline__ void mm6(const bf16x8 (&a)[4], const bf16x8 (&W)[6][4],
                                    f32x4 (&acc)[6], f32x4 (&accn)[2]) {
#pragma unroll
  for (int tI = 0; tI < 6; ++tI)
#pragma unroll
    for (int kq = 0; kq < 4; ++kq) {
      if (NSEP && tI >= 4) accn[tI - 4] = MFMA(a[kq], W[tI][kq], accn[tI - 4]);
      else                 acc[tI]      = MFMA(a[kq], W[tI][kq], acc[tI]);
    }
}

__global__ __launch_bounds__(256, 1) void gru2_v1(
    const float* __restrict__ x,
    const float* __restrict__ Wih0, const float* __restrict__ Whh0,
    const float* __restrict__ bih0, const float* __restrict__ bhh0,
    const float* __restrict__ Wih1, const float* __restrict__ Whh1,
    const float* __restrict__ bih1, const float* __restrict__ bhh1,
    const float* __restrict__ Wout, const float* __restrict__ bout,
    float* __restrict__ out)
{
  __shared__ short h0hi[2][BC * PAD], h0lo[2][BC * PAD];
  __shared__ short h1hi[2][BC * PAD], h1lo[2][BC * PAD];
  __shared__ short xbhi[2][BC * PAD], xblo[2][BC * PAD];

  const int tid = threadIdx.x, w = tid >> 6, lane = tid & 63;
  const int nw = lane & 15, quad = lane >> 4, u0 = w * 32;
  const int b0 = blockIdx.x * BC;

  for (int i = tid; i < BC * PAD; i += 256) {
    h0hi[0][i] = 0; h0lo[0][i] = 0; h1hi[0][i] = 0; h1lo[0][i] = 0;
  }
  const size_t xelem = (size_t)(b0 + (tid >> 4)) * (size_t)(S_LEN * D_IN) + (size_t)((tid & 15) * 8);
  const int xsoff = (tid >> 4) * PAD + (tid & 15) * 8;

  auto load_x = [&](int t, bf16x8& xhi, bf16x8& xlo) {
    const size_t o = xelem + (size_t)t * D_IN;
    float4 v0 = *(const float4*)(x + o), v1 = *(const float4*)(x + o + 4);
    float v[8] = {v0.x, v0.y, v0.z, v0.w, v1.x, v1.y, v1.z, v1.w};
#pragma unroll
    for (int e = 0; e < 8; ++e) {
      short h = f2bf(v[e]); xhi[e] = h; xlo[e] = f2bf(v[e] - bf2f(h));
    }
  };
  { bf16x8 xh, xl; load_x(0, xh, xl);
    *(bf16x8*)&xbhi[0][xsoff] = xh; *(bf16x8*)&xblo[0][xsoff] = xl; }

  float brz0[4], bn0[4], brz1[4], bn1[4];
#pragma unroll
  for (int i = 0; i < 2; ++i) {
    const int c = u0 + i * 16 + nw;
    brz0[i] = bih0[c] + bhh0[c];     brz0[2 + i] = bih0[128 + c] + bhh0[128 + c];
    bn0[i] = bih0[256 + c];          bn0[2 + i] = bhh0[256 + c];
    brz1[i] = bih1[c] + bhh1[c];     brz1[2 + i] = bih1[128 + c] + bhh1[128 + c];
    bn1[i] = bih1[256 + c];          bn1[2 + i] = bhh1[256 + c];
  }

  bf16x8 W0[6][4], Wh0f[6][4], W1[6][4], Wh1f[6][4];
#pragma unroll
  for (int tI = 0; tI < 6; ++tI) {
    const int rb = (tI >> 1) * 128 + u0 + (tI & 1) * 16 + nw;
#pragma unroll
    for (int kq = 0; kq < 4; ++kq) {
      const size_t o = (size_t)rb * HID + kq * 32 + quad * 8;
#pragma unroll
      for (int e = 0; e < 8; ++e) {
        W0[tI][kq][e] = f2bf(Wih0[o + e]);  Wh0f[tI][kq][e] = f2bf(Whh0[o + e]);
        W1[tI][kq][e] = f2bf(Wih1[o + e]);  Wh1f[tI][kq][e] = f2bf(Whh1[o + e]);
      }
    }
  }

  f32x4 h0reg[2] = {{0,0,0,0},{0,0,0,0}}, h1reg[2] = {{0,0,0,0},{0,0,0,0}};
  const f32x4 ZV = {0.f, 0.f, 0.f, 0.f};
  __syncthreads();
  const int aoff = nw * PAD + quad * 8;

  auto gates = [&](const f32x4 (&acc)[6], const f32x4 (&accn)[2], f32x4 (&hreg)[2],
                   const float (&brz)[4], const float (&bn)[4],
                   short* dhi, short* dlo) {
#pragma unroll
    for (int i = 0; i < 2; ++i) {
      const int c = u0 + i * 16 + nw;
#pragma unroll
      for (int rr = 0; rr < 4; ++rr) {
        float rv = fast_sigmoid(acc[i][rr] + brz[i]);
        float zv = fast_sigmoid(acc[2 + i][rr] + brz[2 + i]);
        float nv = fast_tanh((acc[4 + i][rr] + bn[i]) + rv * (accn[i][rr] + bn[2 + i]));
        float h = (1.f - zv) * nv + zv * hreg[i][rr];
        hreg[i][rr] = h;
        short hi = f2bf(h);
        const int row = quad * 4 + rr;
        dhi[row * PAD + c] = hi;
        dlo[row * PAD + c] = f2bf(h - bf2f(hi));
      }
    }
  };

  for (int t = 0; t < S_LEN; ++t) {
    const int pr = t & 1, pw = pr ^ 1;
    const int t1 = (t + 1 < S_LEN) ? t + 1 : t;
    bf16x8 xh, xl; load_x(t1, xh, xl);

    f32x4 acc[6], accn[2];
#pragma unroll
    for (int i = 0; i < 6; ++i) acc[i] = ZV;
#pragma unroll
    for (int i = 0; i < 2; ++i) accn[i] = ZV;
    bf16x8 a[4];
    loadA(a, &xbhi[pr][aoff]); mm6<false>(a, W0, acc, accn);
    loadA(a, &xblo[pr][aoff]); mm6<false>(a, W0, acc, accn);
    loadA(a, &h0hi[pr][aoff]); mm6<true >(a, Wh0f, acc, accn);
    loadA(a, &h0lo[pr][aoff]); mm6<true >(a, Wh0f, acc, accn);
    gates(acc, accn, h0reg, brz0, bn0, h0hi[pw], h0lo[pw]);
    __syncthreads();

#pragma unroll
    for (int i = 0; i < 6; ++i) acc[i] = ZV;
#pragma unroll
    for (int i = 0; i < 2; ++i) accn[i] = ZV;
    loadA(a, &h0hi[pw][aoff]); mm6<false>(a, W1, acc, accn);
    loadA(a, &h0lo[pw][aoff]); mm6<false>(a, W1, acc, accn);
    loadA(a, &h1hi[pr][aoff]); mm6<true >(a, Wh1f, acc, accn);
    loadA(a, &h1lo[pr][aoff]); mm6<true >(a, Wh1f, acc, accn);
    *(bf16x8*)&xbhi[pw][xsoff] = xh;
    *(bf16x8*)&xblo[pw][xsoff] = xl;
    gates(acc, accn, h1reg, brz1, bn1, h1hi[pw], h1lo[pw]);
    __syncthreads();
  }

  if (tid < BC * 10) {
    const int b = tid / 10, c = tid % 10;
    float s = bout[c];
    const short* hh = &h1hi[0][b * PAD];
    const short* hl = &h1lo[0][b * PAD];
#pragma unroll 8
    for (int k = 0; k < HID; ++k)
      s += (bf2f(hh[k]) + bf2f(hl[k])) * Wout[c * HID + k];
    out[(size_t)(b0 + b) * 10 + c] = s;
  }
}

// ============================ Host =========================================
extern "C" void kernel_launch(void* const* d_in, const int* in_sizes, int n_in,
                              void* d_out, int out_size, void* d_ws, size_t ws_size,
                              hipStream_t stream) {
  (void)in_sizes; (void)n_in; (void)out_size;
  const float* x    = (const float*)d_in[0];
  const float* Wih0 = (const float*)d_in[1];
  const float* Whh0 = (const float*)d_in[2];
  const float* bih0 = (const float*)d_in[3];
  const float* bhh0 = (const float*)d_in[4];
  const float* Wih1 = (const float*)d_in[5];
  const float* Whh1 = (const float*)d_in[6];
  const float* bih1 = (const float*)d_in[7];
  const float* bhh1 = (const float*)d_in[8];
  const float* Wout = (const float*)d_in[9];
  const float* bout = (const float*)d_in[10];
  float* out = (float*)d_out;

  const size_t XPB = (size_t)M_TOT * G3 * sizeof(_Float16);   // 192 MiB

  if (ws_size >= XPB) {
    _Float16* xp0 = (_Float16*)d_ws;
    xp0_gemm<<<dim3(M_TOT / 64), dim3(256), 0, stream>>>(
        x, Wih0, bih0, bhh0, xp0);
    gru2_pc<<<dim3(B_TOT / BC), dim3(768), 0, stream>>>(
        xp0, Whh0, bhh0, Wih1, Whh1, bih1, bhh1, Wout, bout, out);
  } else {
    gru2_v1<<<dim3(B_TOT / BC), dim3(256), 0, stream>>>(
        x, Wih0, Whh0, bih0, bhh0, Wih1, Whh1, bih1, bhh1, Wout, bout, out);
  }
}

// Round 9
// 6058.339 us; speedup vs baseline: 1.4062x; 1.3971x over previous
//
#include <hip/hip_runtime.h>
#include <hip/hip_bf16.h>

// 2-layer GRU, B=128, S=2048, D=H=128, C=10. Inputs fp32.
//
// Phase 1 (all CUs): xp0[m,g] = x@W_ih0^T + biases, fp16 in d_ws (192 MiB).
// Phase 2: INTRA-WG producer/consumer wave split, 8 WGs x 1024 threads
//   (16 waves, 4/SIMD). Per WG (16 batch rows):
//     waves 0-7  (P): L0 chain, 16 cols each: Whh0 MFMA (12) + gates;
//        h0 double-buffered in LDS; xp0 prefetch depth-2 (packed fp16).
//        ~100 VGPR -> fully register-resident under the 128 budget.
//     waves 8-15 (C): L1 chain, lagged one step: Wi1@h0(t-1) + Wh1@h1(t-2)
//        (24 MFMA) + gates; ~140 VGPR -> mild spill only.
//   WHY THIS SHAPE (R5-R7 lesson): the VGPR budget is set by the compiler's
//   achievable-occupancy calc (threads+LDS), not by launch_bounds hints.
//   768-thr/17KB allowed 2 WGs/CU -> 6 waves/SIMD -> 85-reg budget -> all
//   weights spilled (8.3 ms). Here: 1024 thr + LDS padded >80KB -> max
//   1 WG/CU -> exactly 4 waves/SIMD -> hard 128-reg budget.
//   (R8 bench died at container level before measuring this; no hang
//   mechanism found on audit — barrier counts equal on both paths, no
//   spin-waits, 87KB LDS/WG is legal on gfx950. Re-submitting.)
// Fallback: ws < XPB: proven single-kernel bf16 path (gru2_v1).

using bf16x8 = __attribute__((ext_vector_type(8))) short;
using s16x4  = __attribute__((ext_vector_type(4))) short;
using f32x4  = __attribute__((ext_vector_type(4))) float;
using f16x8  = __attribute__((ext_vector_type(8))) _Float16;
using f16x4  = __attribute__((ext_vector_type(4))) _Float16;

#define S_LEN 2048
#define D_IN  128
#define HID   128
#define B_TOT 128
#define BC    16
#define PAD   136
#define G3    384
#define M_TOT (B_TOT * S_LEN)

__device__ __forceinline__ float bf2f(short s) {
  unsigned int u = ((unsigned int)(unsigned short)s) << 16;
  float f; __builtin_memcpy(&f, &u, 4); return f;
}
__device__ __forceinline__ short f2bf(float f) {  // RNE
  unsigned int u; __builtin_memcpy(&u, &f, 4);
  u += 0x7fffu + ((u >> 16) & 1u);
  return (short)(u >> 16);
}
__device__ __forceinline__ float fast_sigmoid(float x) {
  return __builtin_amdgcn_rcpf(1.f + __expf(-x));
}
__device__ __forceinline__ float fast_tanh(float x) {
  return 2.f * __builtin_amdgcn_rcpf(1.f + __expf(-2.f * x)) - 1.f;
}
__device__ __forceinline__ f32x4 MFMA(bf16x8 a, bf16x8 b, f32x4 c) {
  return __builtin_amdgcn_mfma_f32_16x16x32_bf16(a, b, c, 0, 0, 0);
}
__device__ __forceinline__ f32x4 MFMA16(f16x8 a, f16x8 b, f32x4 c) {
  return __builtin_amdgcn_mfma_f32_16x16x32_f16(a, b, c, 0, 0, 0);
}
__device__ __forceinline__ void loadA(bf16x8 (&a)[4], const short* p) {
#pragma unroll
  for (int kq = 0; kq < 4; ++kq) a[kq] = *(const bf16x8*)(p + kq * 32);
}
__device__ __forceinline__ void loadA16(f16x8 (&a)[4], const _Float16* p) {
#pragma unroll
  for (int kq = 0; kq < 4; ++kq) a[kq] = *(const f16x8*)(p + kq * 32);
}
// Workgroup barrier WITHOUT the vmcnt(0) drain __syncthreads would emit.
__device__ __forceinline__ void wg_barrier() {
  asm volatile("s_waitcnt lgkmcnt(0)\n\ts_barrier" ::: "memory");
}
// unpack one fp16 half (lo/hi) of a packed u32 to float
__device__ __forceinline__ float f16p(unsigned pk, int hi) {
  unsigned short s = hi ? (unsigned short)(pk >> 16) : (unsigned short)pk;
  _Float16 h; __builtin_memcpy(&h, &s, 2); return (float)h;
}

// ============================ Phase 1 =====================================
__global__ __launch_bounds__(256, 1) void xp0_gemm(
    const float* __restrict__ x, const float* __restrict__ Wih0,
    const float* __restrict__ bih0, const float* __restrict__ bhh0,
    _Float16* __restrict__ xp0)
{
  __shared__ _Float16 wlds[96 * PAD];
  __shared__ float bfold[G3];

  const int tid = threadIdx.x;
  const int w = tid >> 6, lane = tid & 63, nw = lane & 15, quad = lane >> 4;
  const int m0 = blockIdx.x * 64 + w * 16;

  for (int g = tid; g < G3; g += 256)
    bfold[g] = bih0[g] + (g < 256 ? bhh0[g] : 0.f);

  f16x8 af[4];
  const int arow = m0 + nw;
#pragma unroll
  for (int kq = 0; kq < 4; ++kq) {
    const float* p = x + (size_t)arow * D_IN + kq * 32 + quad * 8;
    float4 v0 = *(const float4*)p, v1 = *(const float4*)(p + 4);
    af[kq] = (f16x8){(_Float16)v0.x, (_Float16)v0.y, (_Float16)v0.z, (_Float16)v0.w,
                     (_Float16)v1.x, (_Float16)v1.y, (_Float16)v1.z, (_Float16)v1.w};
  }

  for (int grp = 0; grp < 4; ++grp) {
    __syncthreads();
    for (int i = tid; i < 96 * 128 / 4; i += 256) {
      const int idx = i * 4, row = idx >> 7, cc = idx & 127;
      float4 v = *(const float4*)(Wih0 + (size_t)(grp * 96 + row) * 128 + cc);
      f16x4 s = { (_Float16)v.x, (_Float16)v.y, (_Float16)v.z, (_Float16)v.w };
      *(f16x4*)&wlds[row * PAD + cc] = s;
    }
    __syncthreads();

    f32x4 acc[6];
#pragma unroll
    for (int i = 0; i < 6; ++i) acc[i] = (f32x4){0.f, 0.f, 0.f, 0.f};
#pragma unroll
    for (int tI = 0; tI < 6; ++tI)
#pragma unroll
      for (int kq = 0; kq < 4; ++kq) {
        f16x8 b = *(const f16x8*)&wlds[(tI * 16 + nw) * PAD + kq * 32 + quad * 8];
        acc[tI] = MFMA16(af[kq], b, acc[tI]);
      }

#pragma unroll
    for (int tI = 0; tI < 6; ++tI) {
      const int g = grp * 96 + tI * 16 + nw;
      const float bb = bfold[g];
#pragma unroll
      for (int rr = 0; rr < 4; ++rr) {
        const int m = m0 + quad * 4 + rr;
        xp0[(size_t)m * G3 + g] = (_Float16)(acc[tI][rr] + bb);
      }
    }
  }
}

// ============================ Phase 2 =====================================
__device__ __forceinline__ void mm3f(const f16x8 (&a)[4], const f16x8 (&W)[3][4],
                                     f32x4& r, f32x4& z, f32x4& n) {
#pragma unroll
  for (int kq = 0; kq < 4; ++kq) {
    r = MFMA16(a[kq], W[0][kq], r);
    z = MFMA16(a[kq], W[1][kq], z);
    n = MFMA16(a[kq], W[2][kq], n);
  }
}

// ---------------- intra-WG producer/consumer kernel ------------------------
__global__ __launch_bounds__(1024, 4) void gru2_pc(
    const _Float16* __restrict__ xp0,
    const float* __restrict__ Whh0, const float* __restrict__ bhh0,
    const float* __restrict__ Wih1, const float* __restrict__ Whh1,
    const float* __restrict__ bih1, const float* __restrict__ bhh1,
    const float* __restrict__ Wout, const float* __restrict__ bout,
    float* __restrict__ out)
{
  __shared__ _Float16 h0f[2][BC * PAD];
  __shared__ _Float16 h1f[2][BC * PAD];
  // Occupancy clamp: push LDS past 80 KB so at most ONE 1024-thread WG fits
  // per CU -> compiler budgets VGPRs for exactly 16 waves/CU (4/SIMD, 128
  // regs). Guard write is never executed but not provably dead.
  __shared__ char occ_pad[68 * 1024];
  if ((size_t)out == 1) ((volatile char*)occ_pad)[0] = 1;

  const int tid  = threadIdx.x;
  const int wv   = tid >> 6;        // 0..15
  const int lane = tid & 63;
  const int nw   = lane & 15;
  const int quad = lane >> 4;
  const int b0   = blockIdx.x * BC;
  const int aoff = nw * PAD + quad * 8;

  for (int i = tid; i < 2 * BC * PAD; i += 1024) {
    ((_Float16*)h0f)[i] = (_Float16)0.f;
    ((_Float16*)h1f)[i] = (_Float16)0.f;
  }

  if (wv < 8) {
    // ======================= P: layer-0 chain ============================
    const int u0  = wv * 16;         // this wave's 16-col slice (1 N-tile)
    const int col = u0 + nw;

    f16x8 W0[3][4];                  // Whh0 B-frags, 48 VGPR
#pragma unroll
    for (int g = 0; g < 3; ++g)
#pragma unroll
      for (int kq = 0; kq < 4; ++kq) {
        const size_t o = (size_t)(g * 128 + col) * HID + kq * 32 + quad * 8;
#pragma unroll
        for (int e = 0; e < 8; ++e) W0[g][kq][e] = (_Float16)Whh0[o + e];
      }
    const float b0n_h = bhh0[256 + col];

    // xp0 element offsets for rows b0+quad*4+rr at t=0, col
    unsigned off[4];
#pragma unroll
    for (int rr = 0; rr < 4; ++rr)
      off[rr] = (unsigned)((b0 + quad * 4 + rr) * S_LEN) * G3 + col;

    // packed xp: 3 gates x 4 rows = 12 halfs -> 6 u32
    auto loadPK = [&](unsigned (&P)[6], int t) {
      const unsigned tG = (unsigned)t * G3;
#pragma unroll
      for (int g = 0; g < 3; ++g)
#pragma unroll
        for (int p = 0; p < 2; ++p) {
          unsigned short lo, hi;
          __builtin_memcpy(&lo, &xp0[off[2 * p]     + tG + g * 128], 2);
          __builtin_memcpy(&hi, &xp0[off[2 * p + 1] + tG + g * 128], 2);
          P[g * 2 + p] = (unsigned)lo | ((unsigned)hi << 16);
        }
    };

    unsigned PA[6], PB[6];
    loadPK(PA, 0);
    loadPK(PB, 1);
    f32x4 h0r = {0.f, 0.f, 0.f, 0.f};

    auto pstep = [&](unsigned (&P)[6], const int t, const int pr, const int pw) {
      f16x8 a[4];
      loadA16(a, &h0f[pr][aoff]);           // h0(t-1)
      // acc-init carries xp (r,z) and bias (n) — same op order as R2/R5
      f32x4 ar = { f16p(P[0],0), f16p(P[0],1), f16p(P[1],0), f16p(P[1],1) };
      f32x4 az = { f16p(P[2],0), f16p(P[2],1), f16p(P[3],0), f16p(P[3],1) };
      f32x4 ahn = { b0n_h, b0n_h, b0n_h, b0n_h };
      mm3f(a, W0, ar, az, ahn);
#pragma unroll
      for (int rr = 0; rr < 4; ++rr) {
        float r = fast_sigmoid(ar[rr]);
        float z = fast_sigmoid(az[rr]);
        float pn = f16p(P[4 + (rr >> 1)], rr & 1);
        float n = fast_tanh(pn + r * ahn[rr]);
        float h = n + z * (h0r[rr] - n);
        h0r[rr] = h;
        h0f[pw][(quad * 4 + rr) * PAD + col] = (_Float16)h;
      }
      // depth-2 prefetch: reload this buffer for t+2
      const int tn = (t + 2 < S_LEN) ? t + 2 : t;
      loadPK(P, tn);
    };

    wg_barrier();
#pragma unroll 1
    for (int t2 = 0; t2 < S_LEN; t2 += 2) {
      pstep(PA, t2,     0, 1); wg_barrier();
      pstep(PB, t2 + 1, 1, 0); wg_barrier();
    }
    wg_barrier();   // C epilogue in flight
  } else {
    // ======================= C: layer-1 chain (lag 1) =====================
    const int u0c = (wv - 8) * 16;
    const int col = u0c + nw;

    const float b1r   = bih1[col]       + bhh1[col];
    const float b1z   = bih1[128 + col] + bhh1[128 + col];
    const float b1n_i = bih1[256 + col];
    const float b1n_h = bhh1[256 + col];

    f16x8 Wi1[3][4], Wh1[3][4];      // 96 VGPR
#pragma unroll
    for (int g = 0; g < 3; ++g)
#pragma unroll
      for (int kq = 0; kq < 4; ++kq) {
        const size_t o = (size_t)(g * 128 + col) * HID + kq * 32 + quad * 8;
#pragma unroll
        for (int e = 0; e < 8; ++e) {
          Wi1[g][kq][e] = (_Float16)Wih1[o + e];
          Wh1[g][kq][e] = (_Float16)Whh1[o + e];
        }
      }

    f32x4 h1r = {0.f, 0.f, 0.f, 0.f};

    auto cbody = [&](const int pr, _Float16* dst) {
      f16x8 a[4];
      f32x4 br  = {b1r, b1r, b1r, b1r};
      f32x4 bz  = {b1z, b1z, b1z, b1z};
      f32x4 bxn = {b1n_i, b1n_i, b1n_i, b1n_i};
      f32x4 bhn = {b1n_h, b1n_h, b1n_h, b1n_h};
      loadA16(a, &h0f[pr][aoff]);  mm3f(a, Wi1, br, bz, bxn);   // h0(t-1)
      loadA16(a, &h1f[pr][aoff]);  mm3f(a, Wh1, br, bz, bhn);   // h1(t-2)
#pragma unroll
      for (int rr = 0; rr < 4; ++rr) {
        float r = fast_sigmoid(br[rr]);
        float z = fast_sigmoid(bz[rr]);
        float n = fast_tanh(bxn[rr] + r * bhn[rr]);
        float h = n + z * (h1r[rr] - n);
        h1r[rr] = h;
        dst[(quad * 4 + rr) * PAD + col] = (_Float16)h;
      }
    };

    wg_barrier();
#pragma unroll 1
    for (int t2 = 0; t2 < S_LEN; t2 += 2) {
      // epoch t2 (even): computes L1(t2-1); skip at t2==0 (h1(-1)=0 stays)
      if (t2) cbody(0, h1f[1]);
      wg_barrier();
      cbody(1, h1f[0]);               // epoch t2+1 (odd): L1(t2)
      wg_barrier();
    }
    // epilogue: L1(2047): h0(2047) in h0f[0], h1(2046) in h1f[0] -> h1f[1]
    cbody(0, h1f[1]);
    wg_barrier();
  }

  // logits from final h1 (parity 1)
  if (tid < BC * 10) {
    const int b = tid / 10, c = tid % 10;
    float s = bout[c];
    const _Float16* hh = &h1f[1][b * PAD];
#pragma unroll 8
    for (int k = 0; k < HID; ++k)
      s += (float)hh[k] * Wout[c * HID + k];
    out[(size_t)(b0 + b) * 10 + c] = s;
  }
}

// ==================== Deep fallback: single-kernel, fp32 inputs ============
template<bool NSEP>
__device__ __forceinline__ void mm6(const bf16x8 (&a)[4], const bf16x8 (&W)[6][4],
                                    f32x4 (&acc)[6], f32x4 (&accn)[2]) {
#pragma unroll
  for (int tI = 0; tI < 6; ++tI)
#pragma unroll
    for (int kq = 0; kq < 4; ++kq) {
      if (NSEP && tI >= 4) accn[tI - 4] = MFMA(a[kq], W[tI][kq], accn[tI - 4]);
      else                 acc[tI]      = MFMA(a[kq], W[tI][kq], acc[tI]);
    }
}

__global__ __launch_bounds__(256, 1) void gru2_v1(
    const float* __restrict__ x,
    const float* __restrict__ Wih0, const float* __restrict__ Whh0,
    const float* __restrict__ bih0, const float* __restrict__ bhh0,
    const float* __restrict__ Wih1, const float* __restrict__ Whh1,
    const float* __restrict__ bih1, const float* __restrict__ bhh1,
    const float* __restrict__ Wout, const float* __restrict__ bout,
    float* __restrict__ out)
{
  __shared__ short h0hi[2][BC * PAD], h0lo[2][BC * PAD];
  __shared__ short h1hi[2][BC * PAD], h1lo[2][BC * PAD];
  __shared__ short xbhi[2][BC * PAD], xblo[2][BC * PAD];

  const int tid = threadIdx.x, w = tid >> 6, lane = tid & 63;
  const int nw = lane & 15, quad = lane >> 4, u0 = w * 32;
  const int b0 = blockIdx.x * BC;

  for (int i = tid; i < BC * PAD; i += 256) {
    h0hi[0][i] = 0; h0lo[0][i] = 0; h1hi[0][i] = 0; h1lo[0][i] = 0;
  }
  const size_t xelem = (size_t)(b0 + (tid >> 4)) * (size_t)(S_LEN * D_IN) + (size_t)((tid & 15) * 8);
  const int xsoff = (tid >> 4) * PAD + (tid & 15) * 8;

  auto load_x = [&](int t, bf16x8& xhi, bf16x8& xlo) {
    const size_t o = xelem + (size_t)t * D_IN;
    float4 v0 = *(const float4*)(x + o), v1 = *(const float4*)(x + o + 4);
    float v[8] = {v0.x, v0.y, v0.z, v0.w, v1.x, v1.y, v1.z, v1.w};
#pragma unroll
    for (int e = 0; e < 8; ++e) {
      short h = f2bf(v[e]); xhi[e] = h; xlo[e] = f2bf(v[e] - bf2f(h));
    }
  };
  { bf16x8 xh, xl; load_x(0, xh, xl);
    *(bf16x8*)&xbhi[0][xsoff] = xh; *(bf16x8*)&xblo[0][xsoff] = xl; }

  float brz0[4], bn0[4], brz1[4], bn1[4];
#pragma unroll
  for (int i = 0; i < 2; ++i) {
    const int c = u0 + i * 16 + nw;
    brz0[i] = bih0[c] + bhh0[c];     brz0[2 + i] = bih0[128 + c] + bhh0[128 + c];
    bn0[i] = bih0[256 + c];          bn0[2 + i] = bhh0[256 + c];
    brz1[i] = bih1[c] + bhh1[c];     brz1[2 + i] = bih1[128 + c] + bhh1[128 + c];
    bn1[i] = bih1[256 + c];          bn1[2 + i] = bhh1[256 + c];
  }

  bf16x8 W0[6][4], Wh0f[6][4], W1[6][4], Wh1f[6][4];
#pragma unroll
  for (int tI = 0; tI < 6; ++tI) {
    const int rb = (tI >> 1) * 128 + u0 + (tI & 1) * 16 + nw;
#pragma unroll
    for (int kq = 0; kq < 4; ++kq) {
      const size_t o = (size_t)rb * HID + kq * 32 + quad * 8;
#pragma unroll
      for (int e = 0; e < 8; ++e) {
        W0[tI][kq][e] = f2bf(Wih0[o + e]);  Wh0f[tI][kq][e] = f2bf(Whh0[o + e]);
        W1[tI][kq][e] = f2bf(Wih1[o + e]);  Wh1f[tI][kq][e] = f2bf(Whh1[o + e]);
      }
    }
  }

  f32x4 h0reg[2] = {{0,0,0,0},{0,0,0,0}}, h1reg[2] = {{0,0,0,0},{0,0,0,0}};
  const f32x4 ZV = {0.f, 0.f, 0.f, 0.f};
  __syncthreads();
  const int aoff = nw * PAD + quad * 8;

  auto gates = [&](const f32x4 (&acc)[6], const f32x4 (&accn)[2], f32x4 (&hreg)[2],
                   const float (&brz)[4], const float (&bn)[4],
                   short* dhi, short* dlo) {
#pragma unroll
    for (int i = 0; i < 2; ++i) {
      const int c = u0 + i * 16 + nw;
#pragma unroll
      for (int rr = 0; rr < 4; ++rr) {
        float rv = fast_sigmoid(acc[i][rr] + brz[i]);
        float zv = fast_sigmoid(acc[2 + i][rr] + brz[2 + i]);
        float nv = fast_tanh((acc[4 + i][rr] + bn[i]) + rv * (accn[i][rr] + bn[2 + i]));
        float h = (1.f - zv) * nv + zv * hreg[i][rr];
        hreg[i][rr] = h;
        short hi = f2bf(h);
        const int row = quad * 4 + rr;
        dhi[row * PAD + c] = hi;
        dlo[row * PAD + c] = f2bf(h - bf2f(hi));
      }
    }
  };

  for (int t = 0; t < S_LEN; ++t) {
    const int pr = t & 1, pw = pr ^ 1;
    const int t1 = (t + 1 < S_LEN) ? t + 1 : t;
    bf16x8 xh, xl; load_x(t1, xh, xl);

    f32x4 acc[6], accn[2];
#pragma unroll
    for (int i = 0; i < 6; ++i) acc[i] = ZV;
#pragma unroll
    for (int i = 0; i < 2; ++i) accn[i] = ZV;
    bf16x8 a[4];
    loadA(a, &xbhi[pr][aoff]); mm6<false>(a, W0, acc, accn);
    loadA(a, &xblo[pr][aoff]); mm6<false>(a, W0, acc, accn);
    loadA(a, &h0hi[pr][aoff]); mm6<true >(a, Wh0f, acc, accn);
    loadA(a, &h0lo[pr][aoff]); mm6<true >(a, Wh0f, acc, accn);
    gates(acc, accn, h0reg, brz0, bn0, h0hi[pw], h0lo[pw]);
    __syncthreads();

#pragma unroll
    for (int i = 0; i < 6; ++i) acc[i] = ZV;
#pragma unroll
    for (int i = 0; i < 2; ++i) accn[i] = ZV;
    loadA(a, &h0hi[pw][aoff]); mm6<false>(a, W1, acc, accn);
    loadA(a, &h0lo[pw][aoff]); mm6<false>(a, W1, acc, accn);
    loadA(a, &h1hi[pr][aoff]); mm6<true >(a, Wh1f, acc, accn);
    loadA(a, &h1lo[pr][aoff]); mm6<true >(a, Wh1f, acc, accn);
    *(bf16x8*)&xbhi[pw][xsoff] = xh;
    *(bf16x8*)&xblo[pw][xsoff] = xl;
    gates(acc, accn, h1reg, brz1, bn1, h1hi[pw], h1lo[pw]);
    __syncthreads();
  }

  if (tid < BC * 10) {
    const int b = tid / 10, c = tid % 10;
    float s = bout[c];
    const short* hh = &h1hi[0][b * PAD];
    const short* hl = &h1lo[0][b * PAD];
#pragma unroll 8
    for (int k = 0; k < HID; ++k)
      s += (bf2f(hh[k]) + bf2f(hl[k])) * Wout[c * HID + k];
    out[(size_t)(b0 + b) * 10 + c] = s;
  }
}

// ============================ Host =========================================
extern "C" void kernel_launch(void* const* d_in, const int* in_sizes, int n_in,
                              void* d_out, int out_size, void* d_ws, size_t ws_size,
                              hipStream_t stream) {
  (void)in_sizes; (void)n_in; (void)out_size;
  const float* x    = (const float*)d_in[0];
  const float* Wih0 = (const float*)d_in[1];
  const float* Whh0 = (const float*)d_in[2];
  const float* bih0 = (const float*)d_in[3];
  const float* bhh0 = (const float*)d_in[4];
  const float* Wih1 = (const float*)d_in[5];
  const float* Whh1 = (const float*)d_in[6];
  const float* bih1 = (const float*)d_in[7];
  const float* bhh1 = (const float*)d_in[8];
  const float* Wout = (const float*)d_in[9];
  const float* bout = (const float*)d_in[10];
  float* out = (float*)d_out;

  const size_t XPB = (size_t)M_TOT * G3 * sizeof(_Float16);   // 192 MiB

  if (ws_size >= XPB) {
    _Float16* xp0 = (_Float16*)d_ws;
    xp0_gemm<<<dim3(M_TOT / 64), dim3(256), 0, stream>>>(
        x, Wih0, bih0, bhh0, xp0);
    gru2_pc<<<dim3(B_TOT / BC), dim3(1024), 0, stream>>>(
        xp0, Whh0, bhh0, Wih1, Whh1, bih1, bhh1, Wout, bout, out);
  } else {
    gru2_v1<<<dim3(B_TOT / BC), dim3(256), 0, stream>>>(
        x, Wih0, Whh0, bih0, bhh0, Wih1, Whh1, bih1, bhh1, Wout, bout, out);
  }
}

// Round 10
// 2162.187 us; speedup vs baseline: 3.9400x; 2.8019x over previous
//
#include <hip/hip_runtime.h>
#include <hip/hip_bf16.h>

// 2-layer GRU, B=128, S=2048, D=H=128, C=10. Inputs fp32.
//
// Phase 1 (all CUs): xp0[m,g] = x@W_ih0^T + biases, fp16 in d_ws (192 MiB).
// Phase 2: R4's proven producer/consumer split across 16 WGs (16 CUs),
//   512 thr each (__launch_bounds__(512,2) -> the empirically-honored
//   128-VGPR shape; R5-R9 showed the allocator targets ~1024/WG_waves regs
//   regardless of hints, so >8-wave WGs always spill).
//   NEW (this round): C-side software pipelining. Wi1@h0(t) does not depend
//   on h1 -> computed at step t-1 into persistent accumulators xp1{r,z,n}
//   (+12 VGPR, ~120 total). In-step critical path shrinks to
//   ds_read h1 -> 12 MFMA -> gates -> write (was 24 MFMA + A-wait).
//   FP accumulation order unchanged (Wi1 terms then Wh1 terms) -> absmax
//   identical.
// Fallbacks: ws >= XPB: R2 fused kernel; else: single-kernel bf16 path.

using bf16x8 = __attribute__((ext_vector_type(8))) short;
using s16x4  = __attribute__((ext_vector_type(4))) short;
using f32x4  = __attribute__((ext_vector_type(4))) float;
using f16x8  = __attribute__((ext_vector_type(8))) _Float16;
using f16x4  = __attribute__((ext_vector_type(4))) _Float16;
using u32x2  = __attribute__((ext_vector_type(2))) unsigned int;

#define S_LEN 2048
#define D_IN  128
#define HID   128
#define B_TOT 128
#define BC    16
#define PAD   136
#define G3    384
#define M_TOT (B_TOT * S_LEN)

#define CH    32                       // steps per chunk (flag cadence)
#define WIN   4                        // ring slots (chunks in flight)
#define TILE_HALFS (BC * HID)          // 2048 halfs = 4KB per step-tile
#define WGWIN_HALFS (WIN * CH * TILE_HALFS)

__device__ __forceinline__ float bf2f(short s) {
  unsigned int u = ((unsigned int)(unsigned short)s) << 16;
  float f; __builtin_memcpy(&f, &u, 4); return f;
}
__device__ __forceinline__ short f2bf(float f) {  // RNE
  unsigned int u; __builtin_memcpy(&u, &f, 4);
  u += 0x7fffu + ((u >> 16) & 1u);
  return (short)(u >> 16);
}
__device__ __forceinline__ float fast_sigmoid(float x) {
  return __builtin_amdgcn_rcpf(1.f + __expf(-x));
}
__device__ __forceinline__ float fast_tanh(float x) {
  return 2.f * __builtin_amdgcn_rcpf(1.f + __expf(-2.f * x)) - 1.f;
}
__device__ __forceinline__ f32x4 MFMA(bf16x8 a, bf16x8 b, f32x4 c) {
  return __builtin_amdgcn_mfma_f32_16x16x32_bf16(a, b, c, 0, 0, 0);
}
__device__ __forceinline__ f32x4 MFMA16(f16x8 a, f16x8 b, f32x4 c) {
  return __builtin_amdgcn_mfma_f32_16x16x32_f16(a, b, c, 0, 0, 0);
}
__device__ __forceinline__ void loadA(bf16x8 (&a)[4], const short* p) {
#pragma unroll
  for (int kq = 0; kq < 4; ++kq) a[kq] = *(const bf16x8*)(p + kq * 32);
}
__device__ __forceinline__ void loadA16(f16x8 (&a)[4], const _Float16* p) {
#pragma unroll
  for (int kq = 0; kq < 4; ++kq) a[kq] = *(const f16x8*)(p + kq * 32);
}
// Workgroup barrier WITHOUT the vmcnt(0) drain __syncthreads would emit.
__device__ __forceinline__ void wg_barrier() {
  asm volatile("s_waitcnt lgkmcnt(0)\n\ts_barrier" ::: "memory");
}
__device__ __forceinline__ int ld_acq(const int* p) {
  return __hip_atomic_load(p, __ATOMIC_ACQUIRE, __HIP_MEMORY_SCOPE_AGENT);
}
__device__ __forceinline__ int ld_rlx(const int* p) {
  return __hip_atomic_load(p, __ATOMIC_RELAXED, __HIP_MEMORY_SCOPE_AGENT);
}
__device__ __forceinline__ void st_rel(int* p, int v) {
  __hip_atomic_store(p, v, __ATOMIC_RELEASE, __HIP_MEMORY_SCOPE_AGENT);
}

// ============================ Phase 1 =====================================
__global__ __launch_bounds__(256, 1) void xp0_gemm(
    const float* __restrict__ x, const float* __restrict__ Wih0,
    const float* __restrict__ bih0, const float* __restrict__ bhh0,
    _Float16* __restrict__ xp0)
{
  __shared__ _Float16 wlds[96 * PAD];
  __shared__ float bfold[G3];

  const int tid = threadIdx.x;
  const int w = tid >> 6, lane = tid & 63, nw = lane & 15, quad = lane >> 4;
  const int m0 = blockIdx.x * 64 + w * 16;

  for (int g = tid; g < G3; g += 256)
    bfold[g] = bih0[g] + (g < 256 ? bhh0[g] : 0.f);

  f16x8 af[4];
  const int arow = m0 + nw;
#pragma unroll
  for (int kq = 0; kq < 4; ++kq) {
    const float* p = x + (size_t)arow * D_IN + kq * 32 + quad * 8;
    float4 v0 = *(const float4*)p, v1 = *(const float4*)(p + 4);
    af[kq] = (f16x8){(_Float16)v0.x, (_Float16)v0.y, (_Float16)v0.z, (_Float16)v0.w,
                     (_Float16)v1.x, (_Float16)v1.y, (_Float16)v1.z, (_Float16)v1.w};
  }

  for (int grp = 0; grp < 4; ++grp) {
    __syncthreads();
    for (int i = tid; i < 96 * 128 / 4; i += 256) {
      const int idx = i * 4, row = idx >> 7, cc = idx & 127;
      float4 v = *(const float4*)(Wih0 + (size_t)(grp * 96 + row) * 128 + cc);
      f16x4 s = { (_Float16)v.x, (_Float16)v.y, (_Float16)v.z, (_Float16)v.w };
      *(f16x4*)&wlds[row * PAD + cc] = s;
    }
    __syncthreads();

    f32x4 acc[6];
#pragma unroll
    for (int i = 0; i < 6; ++i) acc[i] = (f32x4){0.f, 0.f, 0.f, 0.f};
#pragma unroll
    for (int tI = 0; tI < 6; ++tI)
#pragma unroll
      for (int kq = 0; kq < 4; ++kq) {
        f16x8 b = *(const f16x8*)&wlds[(tI * 16 + nw) * PAD + kq * 32 + quad * 8];
        acc[tI] = MFMA16(af[kq], b, acc[tI]);
      }

#pragma unroll
    for (int tI = 0; tI < 6; ++tI) {
      const int g = grp * 96 + tI * 16 + nw;
      const float bb = bfold[g];
#pragma unroll
      for (int rr = 0; rr < 4; ++rr) {
        const int m = m0 + quad * 4 + rr;
        xp0[(size_t)m * G3 + g] = (_Float16)(acc[tI][rr] + bb);
      }
    }
  }
}

// ============================ Phase 2 =====================================
__device__ __forceinline__ void mm3f(const f16x8 (&a)[4], const f16x8 (&W)[3][4],
                                     f32x4& r, f32x4& z, f32x4& n) {
#pragma unroll
  for (int kq = 0; kq < 4; ++kq) {
    r = MFMA16(a[kq], W[0][kq], r);
    z = MFMA16(a[kq], W[1][kq], z);
    n = MFMA16(a[kq], W[2][kq], n);
  }
}
__device__ __forceinline__ void mm3x2f(const f16x8 (&a)[4],
    const f16x8 (&Wa)[3][4], const f16x8 (&Wb)[3][4],
    f32x4& r1, f32x4& z1, f32x4& n1, f32x4& r2, f32x4& z2, f32x4& n2) {
#pragma unroll
  for (int kq = 0; kq < 4; ++kq) {
    r1 = MFMA16(a[kq], Wa[0][kq], r1);
    r2 = MFMA16(a[kq], Wb[0][kq], r2);
    z1 = MFMA16(a[kq], Wa[1][kq], z1);
    z2 = MFMA16(a[kq], Wb[1][kq], z2);
    n1 = MFMA16(a[kq], Wa[2][kq], n1);
    n2 = MFMA16(a[kq], Wb[2][kq], n2);
  }
}

// ---------------- producer/consumer split kernel --------------------------
__global__ __launch_bounds__(512, 2) void gru2_split(
    const _Float16* __restrict__ xp0,
    _Float16* __restrict__ win,            // 8 WGs x WIN x CH x 4KB ring
    int* __restrict__ ctrl,                // [0..7]=flag, [8..15]=consumed
    const float* __restrict__ Whh0, const float* __restrict__ bhh0,
    const float* __restrict__ Wih1, const float* __restrict__ Whh1,
    const float* __restrict__ bih1, const float* __restrict__ bhh1,
    const float* __restrict__ Wout, const float* __restrict__ bout,
    float* __restrict__ out)
{
  __shared__ _Float16 hf[2][BC * PAD];

  const int bid  = blockIdx.x;
  const int role = bid >> 3;        // 0 = L0 producer, 1 = L1 consumer
  const int g    = bid & 7;
  const int tid  = threadIdx.x;
  const int w    = tid >> 6;
  const int lane = tid & 63;
  const int nw   = lane & 15;
  const int quad = lane >> 4;
  const int col  = w * 16 + nw;
  const int b0   = g * BC;
  const int aoff = nw * PAD + quad * 8;

  int* flagp = ctrl + g;
  int* consp = ctrl + 8 + g;
  _Float16* win_g = win + (size_t)g * WGWIN_HALFS;

  for (int i = tid; i < 2 * BC * PAD; i += 512)
    ((_Float16*)hf)[i] = (_Float16)0.f;

  if (role == 0) {
    // =========================== L0 producer =============================
    const float b0n_h = bhh0[256 + col];
    f16x8 Wh0[3][4];
#pragma unroll
    for (int gg = 0; gg < 3; ++gg)
#pragma unroll
      for (int kq = 0; kq < 4; ++kq) {
        const size_t o = (size_t)(gg * 128 + col) * HID + kq * 32 + quad * 8;
#pragma unroll
        for (int e = 0; e < 8; ++e) Wh0[gg][kq][e] = (_Float16)Whh0[o + e];
      }

    size_t xbase[4];
#pragma unroll
    for (int rr = 0; rr < 4; ++rr)
      xbase[rr] = (size_t)(b0 + quad * 4 + rr) * S_LEN * G3 + col;

    float PA[12], PB[12];
#pragma unroll
    for (int gg = 0; gg < 3; ++gg)
#pragma unroll
      for (int rr = 0; rr < 4; ++rr)
        PA[gg * 4 + rr] = (float)xp0[xbase[rr] + gg * 128];

    f32x4 h0r = {0.f, 0.f, 0.f, 0.f};
    const int cpo = (tid >> 5) * PAD + ((4 * tid) & 127);  // de-pad copy src
    int cons_seen = 0;
    __syncthreads();

    auto pstep = [&](float (&P)[12], float (&Pn)[12], const int t,
                     const int pr, const int pw) {
      if ((t & (CH - 1)) == 0) {             // ring backpressure
        const int need = (t >> 5) - (WIN - 1);
        if (need > 0 && cons_seen < need) {
          do { cons_seen = ld_rlx(consp);
               if (cons_seen < need) __builtin_amdgcn_s_sleep(8);
          } while (cons_seen < need);
        }
      }
      const int tn = (t + 1 < S_LEN) ? t + 1 : t;
#pragma unroll
      for (int gg = 0; gg < 3; ++gg)
#pragma unroll
        for (int rr = 0; rr < 4; ++rr)
          Pn[gg * 4 + rr] = (float)xp0[xbase[rr] + (size_t)tn * G3 + gg * 128];

      f32x4 ar = {P[0], P[1], P[2], P[3]};
      f32x4 az = {P[4], P[5], P[6], P[7]};
      f32x4 ahn = {b0n_h, b0n_h, b0n_h, b0n_h};
      f16x8 a[4];
      loadA16(a, &hf[pr][aoff]);
      mm3f(a, Wh0, ar, az, ahn);
#pragma unroll
      for (int rr = 0; rr < 4; ++rr) {
        float r = fast_sigmoid(ar[rr]);
        float z = fast_sigmoid(az[rr]);
        float n = fast_tanh(P[8 + rr] + r * ahn[rr]);
        float h = n + z * (h0r[rr] - n);
        h0r[rr] = h;
        hf[pw][(quad * 4 + rr) * PAD + col] = (_Float16)h;
      }
      wg_barrier();
      // export h0(t) tile: de-padded, coalesced, nontemporal
      {
        u32x2 v;
        __builtin_memcpy(&v, &hf[pw][cpo], 8);
        _Float16* dst = win_g +
            ((size_t)((t >> 5) & (WIN - 1)) * CH + (t & (CH - 1))) * TILE_HALFS
            + 4 * tid;
        __builtin_nontemporal_store(v, (u32x2*)dst);
      }
      if ((t & (CH - 1)) == (CH - 1)) {
        __syncthreads();                      // drains vmcnt(0): stores done
        if (tid == 0) st_rel(flagp, (t >> 5) + 1);
      }
    };

#pragma unroll 1
    for (int tt = 0; tt < S_LEN; tt += 2) {
      pstep(PA, PB, tt,     0, 1);
      pstep(PB, PA, tt + 1, 1, 0);
    }
  } else {
    // =========================== L1 consumer =============================
    const float b1r   = bih1[col]       + bhh1[col];
    const float b1z   = bih1[128 + col] + bhh1[128 + col];
    const float b1n_i = bih1[256 + col];
    const float b1n_h = bhh1[256 + col];

    f16x8 Wi1[3][4], Wh1[3][4];
#pragma unroll
    for (int gg = 0; gg < 3; ++gg)
#pragma unroll
      for (int kq = 0; kq < 4; ++kq) {
        const size_t o = (size_t)(gg * 128 + col) * HID + kq * 32 + quad * 8;
#pragma unroll
        for (int e = 0; e < 8; ++e) {
          Wi1[gg][kq][e] = (_Float16)Wih1[o + e];
          Wh1[gg][kq][e] = (_Float16)Whh1[o + e];
        }
      }

    const int afroff = nw * 128 + quad * 8;   // A-frag offset within tile
    f32x4 h1r = {0.f, 0.f, 0.f, 0.f};
    int seen = 0;
    __syncthreads();

    // Prologue: wait chunk 0; precompute xp1(0) = b + Wi1@h0(0); prefetch A(1)
    while (seen < 1) { seen = ld_acq(flagp);
                       if (seen < 1) __builtin_amdgcn_s_sleep(8); }
    f16x8 Anext[4];
    f32x4 xp1r = {b1r, b1r, b1r, b1r};
    f32x4 xp1z = {b1z, b1z, b1z, b1z};
    f32x4 xp1n = {b1n_i, b1n_i, b1n_i, b1n_i};
    {
      f16x8 A0[4];
#pragma unroll
      for (int kq = 0; kq < 4; ++kq)
        A0[kq] = *(const f16x8*)(win_g + afroff + kq * 32);
      mm3f(A0, Wi1, xp1r, xp1z, xp1n);
    }
#pragma unroll
    for (int kq = 0; kq < 4; ++kq)
      Anext[kq] = *(const f16x8*)(win_g + TILE_HALFS + afroff + kq * 32);

    auto cstep = [&](const int t, const int pr, const int pw) {
      if ((t & (CH - 1)) == 0 && tid == 0) st_rel(consp, t >> 5);
      // ---- critical path: h1(t-1) matmul + gates (12 MFMA only) ----
      f16x8 hfr[4];
      loadA16(hfr, &hf[pr][aoff]);
      f32x4 br  = xp1r;
      f32x4 bz  = xp1z;
      f32x4 bxn = xp1n;
      f32x4 bhn = {b1n_h, b1n_h, b1n_h, b1n_h};
      mm3f(hfr, Wh1, br, bz, bhn);
#pragma unroll
      for (int rr = 0; rr < 4; ++rr) {
        float r = fast_sigmoid(br[rr]);
        float z = fast_sigmoid(bz[rr]);
        float n = fast_tanh(bxn[rr] + r * bhn[rr]);
        float h = n + z * (h1r[rr] - n);
        h1r[rr] = h;
        hf[pw][(quad * 4 + rr) * PAD + col] = (_Float16)h;
      }
      // ---- off-path: xp1(t+1) from Anext = A(t+1) (already in regs) ----
      xp1r = (f32x4){b1r, b1r, b1r, b1r};
      xp1z = (f32x4){b1z, b1z, b1z, b1z};
      xp1n = (f32x4){b1n_i, b1n_i, b1n_i, b1n_i};
      mm3f(Anext, Wi1, xp1r, xp1z, xp1n);
      // ---- refill Anext = A(t+2) (flag for its chunk; 1-step latency slack)
      const int tp2 = (t + 2 < S_LEN) ? t + 2 : S_LEN - 1;
      const int cn2 = (tp2 >> 5) + 1;
      if (seen < cn2) {
        do { seen = ld_acq(flagp);
             if (seen < cn2) __builtin_amdgcn_s_sleep(8);
        } while (seen < cn2);
      }
      {
        const _Float16* tp = win_g +
            ((size_t)((tp2 >> 5) & (WIN - 1)) * CH + (tp2 & (CH - 1))) * TILE_HALFS
            + afroff;
#pragma unroll
        for (int kq = 0; kq < 4; ++kq) Anext[kq] = *(const f16x8*)(tp + kq * 32);
      }
      wg_barrier();
    };

#pragma unroll 1
    for (int tt = 0; tt < S_LEN; tt += 2) {
      cstep(tt,     0, 1);
      cstep(tt + 1, 1, 0);
    }

    // logits from final h1: t=2047 wrote parity 0 (barrier already passed)
    if (tid < BC * 10) {
      const int b = tid / 10, c = tid % 10;
      float s = bout[c];
      const _Float16* hh = &hf[0][b * PAD];
#pragma unroll 8
      for (int k = 0; k < HID; ++k)
        s += (float)hh[k] * Wout[c * HID + k];
      out[(size_t)(b0 + b) * 10 + c] = s;
    }
  }
}

// ---------------- R2 fused kernel (mid fallback, ws >= XPB) ---------------
__global__ __launch_bounds__(512, 2) void gru2_rec(
    const _Float16* __restrict__ xp0,
    const float* __restrict__ Whh0, const float* __restrict__ bhh0,
    const float* __restrict__ Wih1, const float* __restrict__ Whh1,
    const float* __restrict__ bih1, const float* __restrict__ bhh1,
    const float* __restrict__ Wout, const float* __restrict__ bout,
    float* __restrict__ out)
{
  __shared__ _Float16 h0f[2][BC * PAD];
  __shared__ _Float16 h1f[2][BC * PAD];

  const int tid  = threadIdx.x;
  const int w    = tid >> 6;
  const int lane = tid & 63;
  const int nw   = lane & 15;
  const int quad = lane >> 4;
  const int col  = w * 16 + nw;
  const int b0   = blockIdx.x * BC;

  for (int i = tid; i < 2 * BC * PAD; i += 512) {
    ((_Float16*)h0f)[i] = (_Float16)0.f;
    ((_Float16*)h1f)[i] = (_Float16)0.f;
  }

  const float b0n_h = bhh0[256 + col];
  const float b1r   = bih1[col]       + bhh1[col];
  const float b1z   = bih1[128 + col] + bhh1[128 + col];
  const float b1n_i = bih1[256 + col];
  const float b1n_h = bhh1[256 + col];

  f16x8 Wh0[3][4], Wi1[3][4], Wh1[3][4];
#pragma unroll
  for (int g = 0; g < 3; ++g) {
#pragma unroll
    for (int kq = 0; kq < 4; ++kq) {
      const size_t o = (size_t)(g * 128 + col) * HID + kq * 32 + quad * 8;
#pragma unroll
      for (int e = 0; e < 8; ++e) {
        Wh0[g][kq][e] = (_Float16)Whh0[o + e];
        Wi1[g][kq][e] = (_Float16)Wih1[o + e];
        Wh1[g][kq][e] = (_Float16)Whh1[o + e];
      }
    }
  }

  size_t xbase[4];
#pragma unroll
  for (int rr = 0; rr < 4; ++rr)
    xbase[rr] = (size_t)(b0 + quad * 4 + rr) * S_LEN * G3 + col;

  float P[12];
#pragma unroll
  for (int g = 0; g < 3; ++g)
#pragma unroll
    for (int rr = 0; rr < 4; ++rr)
      P[g * 4 + rr] = (float)xp0[xbase[rr] + g * 128];

  f32x4 h0r = {0.f, 0.f, 0.f, 0.f}, h1r = {0.f, 0.f, 0.f, 0.f};
  wg_barrier();

  const int aoff = nw * PAD + quad * 8;

  for (int t = 0; t < S_LEN; ++t) {
    const int pr = t & 1, pw = pr ^ 1;
    const int tn = (t + 1 < S_LEN) ? t + 1 : t;
    float Pn[12];
#pragma unroll
    for (int g = 0; g < 3; ++g)
#pragma unroll
      for (int rr = 0; rr < 4; ++rr)
        Pn[g * 4 + rr] = (float)xp0[xbase[rr] + (size_t)tn * G3 + g * 128];

    f32x4 ar  = {P[0], P[1], P[2], P[3]};
    f32x4 az  = {P[4], P[5], P[6], P[7]};
    f32x4 ahn = {b0n_h, b0n_h, b0n_h, b0n_h};
    f32x4 br  = {b1r, b1r, b1r, b1r};
    f32x4 bz  = {b1z, b1z, b1z, b1z};
    f32x4 bxn = {b1n_i, b1n_i, b1n_i, b1n_i};
    f32x4 bhn = {b1n_h, b1n_h, b1n_h, b1n_h};

    f16x8 a[4];
    loadA16(a, &h0f[pr][aoff]); mm3x2f(a, Wh0, Wi1, ar, az, ahn, br, bz, bxn);
    loadA16(a, &h1f[pr][aoff]); mm3f(a, Wh1, br, bz, bhn);

#pragma unroll
    for (int rr = 0; rr < 4; ++rr) {
      float r = fast_sigmoid(ar[rr]);
      float z = fast_sigmoid(az[rr]);
      float n = fast_tanh(P[8 + rr] + r * ahn[rr]);
      float h = n + z * (h0r[rr] - n);
      h0r[rr] = h;
      h0f[pw][(quad * 4 + rr) * PAD + col] = (_Float16)h;
    }
    if (t) {
#pragma unroll
      for (int rr = 0; rr < 4; ++rr) {
        float r = fast_sigmoid(br[rr]);
        float z = fast_sigmoid(bz[rr]);
        float n = fast_tanh(bxn[rr] + r * bhn[rr]);
        float h = n + z * (h1r[rr] - n);
        h1r[rr] = h;
        h1f[pw][(quad * 4 + rr) * PAD + col] = (_Float16)h;
      }
    }
#pragma unroll
    for (int i = 0; i < 12; ++i) P[i] = Pn[i];
    wg_barrier();
  }

  {
    f32x4 br  = {b1r, b1r, b1r, b1r};
    f32x4 bz  = {b1z, b1z, b1z, b1z};
    f32x4 bxn = {b1n_i, b1n_i, b1n_i, b1n_i};
    f32x4 bhn = {b1n_h, b1n_h, b1n_h, b1n_h};
    f16x8 a[4];
    loadA16(a, &h0f[0][aoff]); mm3f(a, Wi1, br, bz, bxn);
    loadA16(a, &h1f[0][aoff]); mm3f(a, Wh1, br, bz, bhn);
#pragma unroll
    for (int rr = 0; rr < 4; ++rr) {
      float r = fast_sigmoid(br[rr]);
      float z = fast_sigmoid(bz[rr]);
      float n = fast_tanh(bxn[rr] + r * bhn[rr]);
      float h = n + z * (h1r[rr] - n);
      h1f[1][(quad * 4 + rr) * PAD + col] = (_Float16)h;
    }
    wg_barrier();
  }

  if (tid < BC * 10) {
    const int b = tid / 10, c = tid % 10;
    float s = bout[c];
    const _Float16* hh = &h1f[1][b * PAD];
#pragma unroll 8
    for (int k = 0; k < HID; ++k)
      s += (float)hh[k] * Wout[c * HID + k];
    out[(size_t)(b0 + b) * 10 + c] = s;
  }
}

// ==================== Deep fallback: single-kernel, fp32 inputs ============
template<bool NSEP>
__device__ __forceinline__ void mm6(const bf16x8 (&a)[4], const bf16x8 (&W)[6][4],
                                    f32x4 (&acc)[6], f32x4 (&accn)[2]) {
#pragma unroll
  for (int tI = 0; tI < 6; ++tI)
#pragma unroll
    for (int kq = 0; kq < 4; ++kq) {
      if (NSEP && tI >= 4) accn[tI - 4] = MFMA(a[kq], W[tI][kq], accn[tI - 4]);
      else                 acc[tI]      = MFMA(a[kq], W[tI][kq], acc[tI]);
    }
}

__global__ __launch_bounds__(256, 1) void gru2_v1(
    const float* __restrict__ x,
    const float* __restrict__ Wih0, const float* __restrict__ Whh0,
    const float* __restrict__ bih0, const float* __restrict__ bhh0,
    const float* __restrict__ Wih1, const float* __restrict__ Whh1,
    const float* __restrict__ bih1, const float* __restrict__ bhh1,
    const float* __restrict__ Wout, const float* __restrict__ bout,
    float* __restrict__ out)
{
  __shared__ short h0hi[2][BC * PAD], h0lo[2][BC * PAD];
  __shared__ short h1hi[2][BC * PAD], h1lo[2][BC * PAD];
  __shared__ short xbhi[2][BC * PAD], xblo[2][BC * PAD];

  const int tid = threadIdx.x, w = tid >> 6, lane = tid & 63;
  const int nw = lane & 15, quad = lane >> 4, u0 = w * 32;
  const int b0 = blockIdx.x * BC;

  for (int i = tid; i < BC * PAD; i += 256) {
    h0hi[0][i] = 0; h0lo[0][i] = 0; h1hi[0][i] = 0; h1lo[0][i] = 0;
  }
  const size_t xelem = (size_t)(b0 + (tid >> 4)) * (size_t)(S_LEN * D_IN) + (size_t)((tid & 15) * 8);
  const int xsoff = (tid >> 4) * PAD + (tid & 15) * 8;

  auto load_x = [&](int t, bf16x8& xhi, bf16x8& xlo) {
    const size_t o = xelem + (size_t)t * D_IN;
    float4 v0 = *(const float4*)(x + o), v1 = *(const float4*)(x + o + 4);
    float v[8] = {v0.x, v0.y, v0.z, v0.w, v1.x, v1.y, v1.z, v1.w};
#pragma unroll
    for (int e = 0; e < 8; ++e) {
      short h = f2bf(v[e]); xhi[e] = h; xlo[e] = f2bf(v[e] - bf2f(h));
    }
  };
  { bf16x8 xh, xl; load_x(0, xh, xl);
    *(bf16x8*)&xbhi[0][xsoff] = xh; *(bf16x8*)&xblo[0][xsoff] = xl; }

  float brz0[4], bn0[4], brz1[4], bn1[4];
#pragma unroll
  for (int i = 0; i < 2; ++i) {
    const int c = u0 + i * 16 + nw;
    brz0[i] = bih0[c] + bhh0[c];     brz0[2 + i] = bih0[128 + c] + bhh0[128 + c];
    bn0[i] = bih0[256 + c];          bn0[2 + i] = bhh0[256 + c];
    brz1[i] = bih1[c] + bhh1[c];     brz1[2 + i] = bih1[128 + c] + bhh1[128 + c];
    bn1[i] = bih1[256 + c];          bn1[2 + i] = bhh1[256 + c];
  }

  bf16x8 W0[6][4], Wh0f[6][4], W1[6][4], Wh1f[6][4];
#pragma unroll
  for (int tI = 0; tI < 6; ++tI) {
    const int rb = (tI >> 1) * 128 + u0 + (tI & 1) * 16 + nw;
#pragma unroll
    for (int kq = 0; kq < 4; ++kq) {
      const size_t o = (size_t)rb * HID + kq * 32 + quad * 8;
#pragma unroll
      for (int e = 0; e < 8; ++e) {
        W0[tI][kq][e] = f2bf(Wih0[o + e]);  Wh0f[tI][kq][e] = f2bf(Whh0[o + e]);
        W1[tI][kq][e] = f2bf(Wih1[o + e]);  Wh1f[tI][kq][e] = f2bf(Whh1[o + e]);
      }
    }
  }

  f32x4 h0reg[2] = {{0,0,0,0},{0,0,0,0}}, h1reg[2] = {{0,0,0,0},{0,0,0,0}};
  const f32x4 ZV = {0.f, 0.f, 0.f, 0.f};
  __syncthreads();
  const int aoff = nw * PAD + quad * 8;

  auto gates = [&](const f32x4 (&acc)[6], const f32x4 (&accn)[2], f32x4 (&hreg)[2],
                   const float (&brz)[4], const float (&bn)[4],
                   short* dhi, short* dlo) {
#pragma unroll
    for (int i = 0; i < 2; ++i) {
      const int c = u0 + i * 16 + nw;
#pragma unroll
      for (int rr = 0; rr < 4; ++rr) {
        float rv = fast_sigmoid(acc[i][rr] + brz[i]);
        float zv = fast_sigmoid(acc[2 + i][rr] + brz[2 + i]);
        float nv = fast_tanh((acc[4 + i][rr] + bn[i]) + rv * (accn[i][rr] + bn[2 + i]));
        float h = (1.f - zv) * nv + zv * hreg[i][rr];
        hreg[i][rr] = h;
        short hi = f2bf(h);
        const int row = quad * 4 + rr;
        dhi[row * PAD + c] = hi;
        dlo[row * PAD + c] = f2bf(h - bf2f(hi));
      }
    }
  };

  for (int t = 0; t < S_LEN; ++t) {
    const int pr = t & 1, pw = pr ^ 1;
    const int t1 = (t + 1 < S_LEN) ? t + 1 : t;
    bf16x8 xh, xl; load_x(t1, xh, xl);

    f32x4 acc[6], accn[2];
#pragma unroll
    for (int i = 0; i < 6; ++i) acc[i] = ZV;
#pragma unroll
    for (int i = 0; i < 2; ++i) accn[i] = ZV;
    bf16x8 a[4];
    loadA(a, &xbhi[pr][aoff]); mm6<false>(a, W0, acc, accn);
    loadA(a, &xblo[pr][aoff]); mm6<false>(a, W0, acc, accn);
    loadA(a, &h0hi[pr][aoff]); mm6<true >(a, Wh0f, acc, accn);
    loadA(a, &h0lo[pr][aoff]); mm6<true >(a, Wh0f, acc, accn);
    gates(acc, accn, h0reg, brz0, bn0, h0hi[pw], h0lo[pw]);
    __syncthreads();

#pragma unroll
    for (int i = 0; i < 6; ++i) acc[i] = ZV;
#pragma unroll
    for (int i = 0; i < 2; ++i) accn[i] = ZV;
    loadA(a, &h0hi[pw][aoff]); mm6<false>(a, W1, acc, accn);
    loadA(a, &h0lo[pw][aoff]); mm6<false>(a, W1, acc, accn);
    loadA(a, &h1hi[pr][aoff]); mm6<true >(a, Wh1f, acc, accn);
    loadA(a, &h1lo[pr][aoff]); mm6<true >(a, Wh1f, acc, accn);
    *(bf16x8*)&xbhi[pw][xsoff] = xh;
    *(bf16x8*)&xblo[pw][xsoff] = xl;
    gates(acc, accn, h1reg, brz1, bn1, h1hi[pw], h1lo[pw]);
    __syncthreads();
  }

  if (tid < BC * 10) {
    const int b = tid / 10, c = tid % 10;
    float s = bout[c];
    const short* hh = &h1hi[0][b * PAD];
    const short* hl = &h1lo[0][b * PAD];
#pragma unroll 8
    for (int k = 0; k < HID; ++k)
      s += (bf2f(hh[k]) + bf2f(hl[k])) * Wout[c * HID + k];
    out[(size_t)(b0 + b) * 10 + c] = s;
  }
}

// ============================ Host =========================================
extern "C" void kernel_launch(void* const* d_in, const int* in_sizes, int n_in,
                              void* d_out, int out_size, void* d_ws, size_t ws_size,
                              hipStream_t stream) {
  (void)in_sizes; (void)n_in; (void)out_size;
  const float* x    = (const float*)d_in[0];
  const float* Wih0 = (const float*)d_in[1];
  const float* Whh0 = (const float*)d_in[2];
  const float* bih0 = (const float*)d_in[3];
  const float* bhh0 = (const float*)d_in[4];
  const float* Wih1 = (const float*)d_in[5];
  const float* Whh1 = (const float*)d_in[6];
  const float* bih1 = (const float*)d_in[7];
  const float* bhh1 = (const float*)d_in[8];
  const float* Wout = (const float*)d_in[9];
  const float* bout = (const float*)d_in[10];
  float* out = (float*)d_out;

  const size_t XPB  = (size_t)M_TOT * G3 * sizeof(_Float16);       // 192 MiB
  const size_t WINB = 8ull * WGWIN_HALFS * sizeof(_Float16);       //   4 MiB
  const size_t REQ  = XPB + WINB + 64;

  if (ws_size >= REQ) {
    char* ws = (char*)d_ws;
    _Float16* xp0  = (_Float16*)ws;
    _Float16* wing = (_Float16*)(ws + XPB);
    int*      ctrl = (int*)(ws + XPB + WINB);
    (void)hipMemsetAsync(ctrl, 0, 64, stream);   // replay-safe flag reset
    xp0_gemm<<<dim3(M_TOT / 64), dim3(256), 0, stream>>>(
        x, Wih0, bih0, bhh0, xp0);
    gru2_split<<<dim3(16), dim3(512), 0, stream>>>(
        xp0, wing, ctrl, Whh0, bhh0, Wih1, Whh1, bih1, bhh1, Wout, bout, out);
  } else if (ws_size >= XPB) {
    xp0_gemm<<<dim3(M_TOT / 64), dim3(256), 0, stream>>>(
        x, Wih0, bih0, bhh0, (_Float16*)d_ws);
    gru2_rec<<<dim3(B_TOT / BC), dim3(512), 0, stream>>>(
        (const _Float16*)d_ws, Whh0, bhh0, Wih1, Whh1, bih1, bhh1, Wout, bout, out);
  } else {
    gru2_v1<<<dim3(B_TOT / BC), dim3(256), 0, stream>>>(
        x, Wih0, Whh0, bih0, bhh0, Wih1, Whh1, bih1, bhh1, Wout, bout, out);
  }
}